// Round 2
// baseline (370.464 us; speedup 1.0000x reference)
//
#include <hip/hip_runtime.h>

// CCN_2D on MI355X. N=256 vertices, K=16, C0=16, H=32.
// Facts exploited (validated by round-1 exact pass):
//  * CH rows one-hot => T_t[a][b][c] = Fin[j_t, P_t[a], P_t[b], c], P_t[a] = pos of
//    nbrs[i][a] in nbrs[j_t] (or -1).
//  * A = I_16 collapses contract18 to 6 effective weight matrices (prep kernel).
//  * P_t[t] = -1 always (no self-loops) => c17 and d_ttt terms are identically 0.
//  * Layer-1 input is a broadcast of X => T is rank-1: v_a * v_b * X[j,c].
// Design rules from R1 counters: avoid LDS-broadcast operand reads in matmuls
// (weights via uniform s_load from global), parallelize over t (no serial loop).

constexpr int KN = 16, HH = 32, NV = 256, C2 = 32;

// ---------------- prep: effective weights into ws ----------------
// E[0]=Wsb=16*W[g0]+W[g5]+16*sum(W[g6..g14]); E[1]=W[g1]; E[2]=W[g15];
// E[3]=16*W[g2]; E[4]=W[g3]; E[5]=W[g4].
__global__ __launch_bounds__(256)
void ccn_prep(const float* __restrict__ W1, const float* __restrict__ W2,
              float* __restrict__ E1, float* __restrict__ E2)
{
    const int tid = threadIdx.x;
    {
        const int CW = 16 * HH;  // 512
        for (int u = tid; u < CW; u += 256) {
            float acc = 0.f;
            #pragma unroll
            for (int g = 6; g < 15; ++g) acc += W1[g * CW + u];
            E1[0 * CW + u] = 16.f * W1[0 * CW + u] + W1[5 * CW + u] + 16.f * acc;
            E1[1 * CW + u] = W1[1 * CW + u];
            E1[2 * CW + u] = W1[15 * CW + u];
            E1[3 * CW + u] = 16.f * W1[2 * CW + u];
            E1[4 * CW + u] = W1[3 * CW + u];
            E1[5 * CW + u] = W1[4 * CW + u];
        }
    }
    {
        const int CW = C2 * HH;  // 1024
        for (int u = tid; u < CW; u += 256) {
            float acc = 0.f;
            #pragma unroll
            for (int g = 6; g < 15; ++g) acc += W2[g * CW + u];
            E2[0 * CW + u] = 16.f * W2[0 * CW + u] + W2[5 * CW + u] + 16.f * acc;
            E2[1 * CW + u] = W2[1 * CW + u];
            E2[2 * CW + u] = W2[15 * CW + u];
            E2[3 * CW + u] = 16.f * W2[2 * CW + u];
            E2[4 * CW + u] = W2[3 * CW + u];
            E2[5 * CW + u] = W2[4 * CW + u];
        }
    }
}

// ---------------- layer 1: rank-1 closed form ----------------
__global__ __launch_bounds__(256)
void ccn_l1(const float* __restrict__ X, const int* __restrict__ nbrs,
            const float* __restrict__ E1, const float* __restrict__ bias,
            float* __restrict__ F1)
{
    __shared__ float sXA[16][6][HH];   // per-t matvec results (12 KB)
    __shared__ float sX[16][16];
    __shared__ int   s_nbi[16];
    __shared__ int   s_nbj[16][16];
    __shared__ int   s_P[16][16];
    __shared__ int   s_vm[16];
    __shared__ float s_m[16];

    const int tid = threadIdx.x, i = blockIdx.x;
    const int t = tid >> 4, y = tid & 15;

    if (tid < 16) s_nbi[tid] = nbrs[i * 16 + tid];
    __syncthreads();
    const int j = s_nbi[t];
    s_nbj[t][y] = nbrs[j * 16 + y];
    sX[t][y]    = X[j * 16 + y];
    __syncthreads();
    {
        const int tgt = s_nbi[y];
        int p = -1;
        #pragma unroll
        for (int q = 0; q < 16; ++q) if (s_nbj[t][q] == tgt) p = q;
        s_P[t][y] = p;
        unsigned long long bal = __ballot(p >= 0);
        if (y == 0) {
            int vm = (int)((bal >> ((t & 3) * 16)) & 0xFFFFull);
            s_vm[t] = vm;
            s_m[t]  = (float)__popc(vm);
        }
    }
    __syncthreads();
    // XA[tt][g][h] = sum_c X[j_tt, c] * E1[g][c,h]   (3072 outputs, 12/thread)
    for (int u = tid; u < 16 * 6 * HH; u += 256) {
        const int h = u & 31, g = (u >> 5) % 6, tt = u / (6 * HH);
        float acc = 0.f;
        #pragma unroll
        for (int c = 0; c < 16; ++c) acc += sX[tt][c] * E1[g * (16 * HH) + c * HH + h];
        sXA[tt][g][h] = acc;
    }
    __syncthreads();

    float pre[HH];
    const int x = t;
    const float vy = (s_P[t][y] >= 0) ? 1.f : 0.f;
    const float m  = s_m[t];
    #pragma unroll
    for (int h = 0; h < HH; ++h)
        pre[h] = vy * (m * sXA[t][0][h] + sXA[t][2][h]) + m * m * sXA[t][1][h];
    for (int tp = 0; tp < 16; ++tp) {
        const int vm = s_vm[tp];
        const float f2 = (float)((vm >> x) & (vm >> y) & 1);
        const float fb = (float)((vm >> x) & 1) * s_m[tp];
        #pragma unroll
        for (int h = 0; h < HH; ++h)
            pre[h] += f2 * sXA[tp][3][h] + fb * sXA[tp][4][h];
    }
    if (x == y) {
        for (int tp = 0; tp < 16; ++tp) {
            const float f = s_m[tp] * s_m[tp];
            #pragma unroll
            for (int h = 0; h < HH; ++h) pre[h] += f * sXA[tp][5][h];
        }
    }
    float4* dst = (float4*)(F1 + (((size_t)i * 16 + x) * 16 + y) * HH);
    #pragma unroll
    for (int h4 = 0; h4 < HH / 4; ++h4) {
        float a0 = pre[4 * h4 + 0] + bias[4 * h4 + 0];
        float a1 = pre[4 * h4 + 1] + bias[4 * h4 + 1];
        float a2 = pre[4 * h4 + 2] + bias[4 * h4 + 2];
        float a3 = pre[4 * h4 + 3] + bias[4 * h4 + 3];
        dst[h4] = make_float4(a0 > 0.f ? a0 : 0.f, a1 > 0.f ? a1 : 0.f,
                              a2 > 0.f ? a2 : 0.f, a3 > 0.f ? a3 : 0.f);
    }
}

// ---------------- layer 2: t-parallel, owner thread (x=t, y) ----------------
__global__ __launch_bounds__(256)
void ccn_l2(const float* __restrict__ F1, const int* __restrict__ nbrs,
            const float* __restrict__ E2, const float* __restrict__ bias,
            const float* __restrict__ fcw, float* __restrict__ partials)
{
    __shared__ float sR[256][C2 + 4];     // padded rows (36 floats, 16B-aligned)
    __shared__ float s_sumtb[16][C2];
    __shared__ float s_sumall[C2];
    __shared__ int   s_nbi[16];
    __shared__ int   s_nbj[16][16];
    __shared__ int   s_P[256];
    __shared__ float s_red[4];

    const int tid = threadIdx.x, i = blockIdx.x;
    const int t = tid >> 4, y = tid & 15;

    if (tid < 16) s_nbi[tid] = nbrs[i * 16 + tid];
    __syncthreads();
    const int j = s_nbi[t];
    s_nbj[t][y] = nbrs[j * 16 + y];
    __syncthreads();
    {
        const int tgt = s_nbi[y];
        int p = -1;
        #pragma unroll
        for (int q = 0; q < 16; ++q) if (s_nbj[t][q] == tgt) p = q;
        s_P[t * 16 + y] = p;
    }
    __syncthreads();

    // ---- stage 1: R[c] = sum_{b valid} F1[j, p, P[b], c]; D[c] = F1[j, p, p, c]
    float R[C2] __attribute__((aligned(16)));
    float D[C2] __attribute__((aligned(16)));
    #pragma unroll
    for (int c = 0; c < C2; ++c) { R[c] = 0.f; D[c] = 0.f; }
    const int p = s_P[t * 16 + y];
    if (p >= 0) {
        const float* bp = F1 + ((size_t)j * 16 + p) * 16 * C2;
        #pragma unroll 4
        for (int b = 0; b < 16; ++b) {
            const int q = s_P[t * 16 + b];
            if (q >= 0) {
                const float4* s4 = (const float4*)(bp + q * C2);
                float4* R4 = (float4*)R;
                #pragma unroll
                for (int c4 = 0; c4 < C2 / 4; ++c4) {
                    float4 v = s4[c4];
                    R4[c4].x += v.x; R4[c4].y += v.y; R4[c4].z += v.z; R4[c4].w += v.w;
                }
            }
        }
        const float4* d4 = (const float4*)(bp + p * C2);
        #pragma unroll
        for (int c4 = 0; c4 < C2 / 4; ++c4) ((float4*)D)[c4] = d4[c4];
    }

    float pre[HH];
    #pragma unroll
    for (int h = 0; h < HH; ++h) pre[h] = 0.f;

    // row-term matmuls; weights are block-uniform global reads -> s_load
    const float* Wsb = E2;
    const float* Wab = E2 + 1 * C2 * HH;
    const float* W16 = E2 + 2 * C2 * HH;
    #pragma unroll
    for (int c = 0; c < C2; ++c) {
        float sab = R[c];
        sab += __shfl_xor(sab, 1);
        sab += __shfl_xor(sab, 2);
        sab += __shfl_xor(sab, 4);
        sab += __shfl_xor(sab, 8);
        const float rc = R[c], dc = D[c];
        #pragma unroll
        for (int h = 0; h < HH; ++h)
            pre[h] += rc * Wsb[c * HH + h] + sab * Wab[c * HH + h] + dc * W16[c * HH + h];
    }

    // stash R for cross-t reductions
    {
        float4* dst = (float4*)&sR[t * 16 + y][0];
        #pragma unroll
        for (int c4 = 0; c4 < C2 / 4; ++c4) dst[c4] = ((float4*)R)[c4];
    }
    __syncthreads();
    // sumtb[x][c] = sum_t R[t][x][c]
    for (int u = tid; u < 16 * C2; u += 256) {
        const int x2 = u >> 5, c = u & 31;
        float s = 0.f;
        #pragma unroll
        for (int tt = 0; tt < 16; ++tt) s += sR[tt * 16 + x2][c];
        s_sumtb[x2][c] = s;
    }
    __syncthreads();
    if (tid < C2) {
        float s = 0.f;
        #pragma unroll
        for (int x2 = 0; x2 < 16; ++x2) s += s_sumtb[x2][tid];
        s_sumall[tid] = s;
    }
    __syncthreads();

    // ---- stage 2: sumT gather + deferred matmuls. thread = (x=t, y)
    float ST[C2] __attribute__((aligned(16)));
    #pragma unroll
    for (int c = 0; c < C2; ++c) ST[c] = 0.f;
    const int x = t;
    #pragma unroll 4
    for (int tp = 0; tp < 16; ++tp) {
        const int px = s_P[tp * 16 + x], py = s_P[tp * 16 + y];
        if (px >= 0 && py >= 0) {
            const float4* s4 = (const float4*)(F1 + (((size_t)s_nbi[tp] * 16 + px) * 16 + py) * C2);
            float4* S4 = (float4*)ST;
            #pragma unroll
            for (int c4 = 0; c4 < C2 / 4; ++c4) {
                float4 v = s4[c4];
                S4[c4].x += v.x; S4[c4].y += v.y; S4[c4].z += v.z; S4[c4].w += v.w;
            }
        }
    }
    const float* Wt2 = E2 + 3 * C2 * HH;
    const float* Wtb = E2 + 4 * C2 * HH;
    const float* Wal = E2 + 5 * C2 * HH;
    #pragma unroll
    for (int c = 0; c < C2; ++c) {
        const float st = ST[c], sb = s_sumtb[x][c];
        #pragma unroll
        for (int h = 0; h < HH; ++h)
            pre[h] += st * Wt2[c * HH + h] + sb * Wtb[c * HH + h];
    }
    if (x == y) {
        #pragma unroll
        for (int c = 0; c < C2; ++c) {
            const float s = s_sumall[c];
            #pragma unroll
            for (int h = 0; h < HH; ++h) pre[h] += s * Wal[c * HH + h];
        }
    }

    // ---- epilogue: bias, relu, dot fc_w, block reduce
    float local = 0.f;
    #pragma unroll
    for (int h = 0; h < HH; ++h) {
        float v = pre[h] + bias[h];
        v = v > 0.f ? v : 0.f;
        local += v * fcw[h];
    }
    #pragma unroll
    for (int off = 32; off > 0; off >>= 1) local += __shfl_down(local, off, 64);
    if ((tid & 63) == 0) s_red[tid >> 6] = local;
    __syncthreads();
    if (tid == 0) partials[i] = s_red[0] + s_red[1] + s_red[2] + s_red[3];
}

__global__ __launch_bounds__(256)
void ccn_finalize(const float* __restrict__ partials,
                  const float* __restrict__ fc_b,
                  float* __restrict__ out)
{
    float v = partials[threadIdx.x];
    #pragma unroll
    for (int off = 32; off > 0; off >>= 1) v += __shfl_down(v, off, 64);
    __shared__ float s_red[4];
    if ((threadIdx.x & 63) == 0) s_red[threadIdx.x >> 6] = v;
    __syncthreads();
    if (threadIdx.x == 0)
        out[0] = s_red[0] + s_red[1] + s_red[2] + s_red[3] + fc_b[0];
}

extern "C" void kernel_launch(void* const* d_in, const int* in_sizes, int n_in,
                              void* d_out, int out_size, void* d_ws, size_t ws_size,
                              hipStream_t stream) {
    const float* X    = (const float*)d_in[0];
    const int*   nbrs = (const int*)  d_in[1];
    const float* W1   = (const float*)d_in[2];
    const float* b1   = (const float*)d_in[3];
    const float* W2   = (const float*)d_in[4];
    const float* b2   = (const float*)d_in[5];
    const float* fc_w = (const float*)d_in[6];
    const float* fc_b = (const float*)d_in[7];
    float* outp = (float*)d_out;

    float* F1       = (float*)d_ws;                       // 2,097,152 floats (8 MB)
    float* partials = F1 + (size_t)NV * KN * KN * HH;     // 256
    float* E1       = partials + NV;                      // 6*512
    float* E2       = E1 + 6 * 16 * HH;                   // 6*1024

    ccn_prep<<<1, 256, 0, stream>>>(W1, W2, E1, E2);
    ccn_l1<<<NV, 256, 0, stream>>>(X, nbrs, E1, b1, F1);
    ccn_l2<<<NV, 256, 0, stream>>>(F1, nbrs, E2, b2, fc_w, partials);
    ccn_finalize<<<1, 256, 0, stream>>>(partials, fc_b, outp);
}

// Round 3
// 247.812 us; speedup vs baseline: 1.4949x; 1.4949x over previous
//
#include <hip/hip_runtime.h>

// CCN_2D on MI355X. N=256 vertices, K=16, C0=16, H=32.
// Facts (validated by exact passes R1/R2):
//  * CH rows one-hot => T_t[a][b][c] = Fin[j_t, P_t[a], P_t[b], c].
//  * A = I_16 collapses contract18 to 6 effective weight matrices.
//  * P_t[t] = -1 (no self-loops) => c17 / d_ttt terms vanish.
//  * Layer-1 input is broadcast of X => rank-1 closed form, no gathers.
// R2 lessons: branchless masked loads (divergent-if around loads serializes),
// weights only via block-uniform addresses (s_load), LDS rows padded.

constexpr int KN = 16, HH = 32, NV = 256, C2 = 32;

// ---------------- prep: effective weights ----------------
// E[0]=Wsb=16*W[g0]+W[g5]+16*sum(W[g6..g14]); E[1]=Wab=W[g1]; E[2]=W16=W[g15];
// E[3]=Wt2=16*W[g2]; E[4]=Wtb=W[g3]; E[5]=Wal=W[g4].
__global__ __launch_bounds__(256)
void ccn_prep(const float* __restrict__ W1, const float* __restrict__ W2,
              float* __restrict__ E1, float* __restrict__ E2)
{
    const int tid = threadIdx.x;
    {
        const int CW = 16 * HH;  // 512
        for (int u = tid; u < CW; u += 256) {
            float acc = 0.f;
            #pragma unroll
            for (int g = 6; g < 15; ++g) acc += W1[g * CW + u];
            E1[0 * CW + u] = 16.f * W1[0 * CW + u] + W1[5 * CW + u] + 16.f * acc;
            E1[1 * CW + u] = W1[1 * CW + u];
            E1[2 * CW + u] = W1[15 * CW + u];
            E1[3 * CW + u] = 16.f * W1[2 * CW + u];
            E1[4 * CW + u] = W1[3 * CW + u];
            E1[5 * CW + u] = W1[4 * CW + u];
        }
    }
    {
        const int CW = C2 * HH;  // 1024
        for (int u = tid; u < CW; u += 256) {
            float acc = 0.f;
            #pragma unroll
            for (int g = 6; g < 15; ++g) acc += W2[g * CW + u];
            E2[0 * CW + u] = 16.f * W2[0 * CW + u] + W2[5 * CW + u] + 16.f * acc;
            E2[1 * CW + u] = W2[1 * CW + u];
            E2[2 * CW + u] = W2[15 * CW + u];
            E2[3 * CW + u] = 16.f * W2[2 * CW + u];
            E2[4 * CW + u] = W2[3 * CW + u];
            E2[5 * CW + u] = W2[4 * CW + u];
        }
    }
}

// ---------------- layer 1: rank-1 closed form, register matmul ----------------
__global__ __launch_bounds__(256)
void ccn_l1(const float* __restrict__ X, const int* __restrict__ nbrs,
            const float* __restrict__ E1, const float* __restrict__ bias,
            float* __restrict__ F1)
{
    __shared__ int   s_nbi[16];
    __shared__ int   s_nbj[16][17];
    __shared__ int   s_P[16][16];
    __shared__ int   s_vm[16];
    __shared__ float s_m[16];
    __shared__ float sX[16][20];   // pad 20: 16B-aligned rows, conflict-free

    const int tid = threadIdx.x, i = blockIdx.x;
    const int t = tid >> 4, y = tid & 15;

    if (tid < 16) s_nbi[tid] = nbrs[i * 16 + tid];
    __syncthreads();
    const int j = s_nbi[t];
    s_nbj[t][y] = nbrs[j * 16 + y];
    sX[t][y]    = X[j * 16 + y];
    __syncthreads();
    {
        const int tgt = s_nbi[y];
        int p = -1;
        #pragma unroll
        for (int q = 0; q < 16; ++q) if (s_nbj[t][q] == tgt) p = q;
        s_P[t][y] = p;
        unsigned long long bal = __ballot(p >= 0);
        if (y == 0) {
            int vm = (int)((bal >> ((t & 3) * 16)) & 0xFFFFull);
            s_vm[t] = vm;
            s_m[t]  = (float)__popc(vm);
        }
    }
    __syncthreads();

    const int x = t;
    float Y0[16];
    #pragma unroll
    for (int c4 = 0; c4 < 4; ++c4) {
        float4 v = *(const float4*)&sX[t][4 * c4];
        Y0[4*c4+0] = v.x; Y0[4*c4+1] = v.y; Y0[4*c4+2] = v.z; Y0[4*c4+3] = v.w;
    }
    float Z2[16], Z4[16], Z5[16];
    #pragma unroll
    for (int c = 0; c < 16; ++c) { Z2[c] = 0.f; Z4[c] = 0.f; Z5[c] = 0.f; }
    #pragma unroll
    for (int tp = 0; tp < 16; ++tp) {
        const int vm  = s_vm[tp];
        const float mt = s_m[tp];
        const float f2 = (float)((vm >> x) & (vm >> y) & 1);
        const float fb = ((vm >> x) & 1) ? mt : 0.f;
        const float f5 = mt * mt;
        #pragma unroll
        for (int c4 = 0; c4 < 4; ++c4) {
            float4 v = *(const float4*)&sX[tp][4 * c4];
            Z2[4*c4+0] = fmaf(f2, v.x, Z2[4*c4+0]);
            Z2[4*c4+1] = fmaf(f2, v.y, Z2[4*c4+1]);
            Z2[4*c4+2] = fmaf(f2, v.z, Z2[4*c4+2]);
            Z2[4*c4+3] = fmaf(f2, v.w, Z2[4*c4+3]);
            Z4[4*c4+0] = fmaf(fb, v.x, Z4[4*c4+0]);
            Z4[4*c4+1] = fmaf(fb, v.y, Z4[4*c4+1]);
            Z4[4*c4+2] = fmaf(fb, v.z, Z4[4*c4+2]);
            Z4[4*c4+3] = fmaf(fb, v.w, Z4[4*c4+3]);
            Z5[4*c4+0] = fmaf(f5, v.x, Z5[4*c4+0]);
            Z5[4*c4+1] = fmaf(f5, v.y, Z5[4*c4+1]);
            Z5[4*c4+2] = fmaf(f5, v.z, Z5[4*c4+2]);
            Z5[4*c4+3] = fmaf(f5, v.w, Z5[4*c4+3]);
        }
    }
    const float vy  = (s_P[t][y] >= 0) ? 1.f : 0.f;
    const float m   = s_m[t];
    const float a0  = vy * m, a1 = m * m, a2 = vy;
    const float dxy = (x == y) ? 1.f : 0.f;

    float pre[HH];
    #pragma unroll
    for (int h = 0; h < HH; ++h) pre[h] = 0.f;

    const float* Wsb = E1;
    const float* Wab = E1 + 512;
    const float* W16 = E1 + 1024;
    const float* Wt2 = E1 + 1536;
    const float* Wtb = E1 + 2048;
    const float* Wal = E1 + 2560;
    #pragma unroll
    for (int c = 0; c < 16; ++c) {
        const float u0 = a0 * Y0[c], u1 = a1 * Y0[c], u2 = a2 * Y0[c];
        const float z2 = Z2[c], z4 = Z4[c], z5 = dxy * Z5[c];
        #pragma unroll
        for (int h = 0; h < HH; ++h)
            pre[h] += u0 * Wsb[c * HH + h] + u1 * Wab[c * HH + h]
                    + u2 * W16[c * HH + h] + z2 * Wt2[c * HH + h]
                    + z4 * Wtb[c * HH + h] + z5 * Wal[c * HH + h];
    }
    float4* dst = (float4*)(F1 + (((size_t)i * 16 + x) * 16 + y) * HH);
    #pragma unroll
    for (int h4 = 0; h4 < HH / 4; ++h4) {
        float a_ = pre[4*h4+0] + bias[4*h4+0];
        float b_ = pre[4*h4+1] + bias[4*h4+1];
        float c_ = pre[4*h4+2] + bias[4*h4+2];
        float d_ = pre[4*h4+3] + bias[4*h4+3];
        dst[h4] = make_float4(a_ > 0.f ? a_ : 0.f, b_ > 0.f ? b_ : 0.f,
                              c_ > 0.f ? c_ : 0.f, d_ > 0.f ? d_ : 0.f);
    }
}

// ---------------- layer 2: branchless gathers, s_load weights ----------------
__global__ __launch_bounds__(256)
void ccn_l2(const float* __restrict__ F1, const int* __restrict__ nbrs,
            const float* __restrict__ E2, const float* __restrict__ bias,
            const float* __restrict__ fcw, float* __restrict__ partials)
{
    __shared__ float sR[256][36];      // R rows, pad 36 (16B-aligned)
    __shared__ float s_stb[16][36];    // sum_tb
    __shared__ float s_sall[C2];
    __shared__ int   s_nbi[16];
    __shared__ int   s_nbj[16][17];
    __shared__ int   s_P[256];
    __shared__ float s_red[4];

    const int tid = threadIdx.x, i = blockIdx.x;
    const int t = tid >> 4, y = tid & 15;

    if (tid < 16) s_nbi[tid] = nbrs[i * 16 + tid];
    __syncthreads();
    const int j = s_nbi[t];
    s_nbj[t][y] = nbrs[j * 16 + y];
    __syncthreads();
    {
        const int tgt = s_nbi[y];
        int p = -1;
        #pragma unroll
        for (int q = 0; q < 16; ++q) if (s_nbj[t][q] == tgt) p = q;
        s_P[t * 16 + y] = p;
    }
    __syncthreads();

    const int x = t;
    const int p = s_P[t * 16 + y];
    const float mp = (p >= 0) ? 1.f : 0.f;
    const int pc = p >= 0 ? p : 0;
    const float* rowbase = F1 + ((size_t)j * 16 + pc) * 16 * C2;

    // ---- R gather: branchless masked row sums ----
    float R[C2];
    #pragma unroll
    for (int c = 0; c < C2; ++c) R[c] = 0.f;
    #pragma unroll
    for (int b = 0; b < 16; ++b) {
        const int q = s_P[t * 16 + b];
        const float m = (q >= 0) ? mp : 0.f;
        const int qc = q >= 0 ? q : 0;
        const float4* src = (const float4*)(rowbase + qc * C2);
        #pragma unroll
        for (int c4 = 0; c4 < 8; ++c4) {
            float4 v = src[c4];
            R[4*c4+0] = fmaf(m, v.x, R[4*c4+0]);
            R[4*c4+1] = fmaf(m, v.y, R[4*c4+1]);
            R[4*c4+2] = fmaf(m, v.z, R[4*c4+2]);
            R[4*c4+3] = fmaf(m, v.w, R[4*c4+3]);
        }
    }
    #pragma unroll
    for (int c4 = 0; c4 < 8; ++c4)
        *(float4*)&sR[t * 16 + y][4 * c4] =
            make_float4(R[4*c4+0], R[4*c4+1], R[4*c4+2], R[4*c4+3]);

    float pre[HH];
    #pragma unroll
    for (int h = 0; h < HH; ++h) pre[h] = 0.f;

    const float* Wsb = E2;
    const float* Wab = E2 + 1 * C2 * HH;
    const float* W16 = E2 + 2 * C2 * HH;
    const float* Wt2 = E2 + 3 * C2 * HH;
    const float* Wtb = E2 + 4 * C2 * HH;
    const float* Wal = E2 + 5 * C2 * HH;

    // row terms: Wsb (own R), Wab (sab broadcast over y)
    #pragma unroll
    for (int c = 0; c < C2; ++c) {
        float sab = R[c];
        sab += __shfl_xor(sab, 1);
        sab += __shfl_xor(sab, 2);
        sab += __shfl_xor(sab, 4);
        sab += __shfl_xor(sab, 8);
        const float rc = R[c];
        #pragma unroll
        for (int h = 0; h < HH; ++h)
            pre[h] += rc * Wsb[c * HH + h] + sab * Wab[c * HH + h];
    }
    // diag term W16: D[c] = T[x,y,y,c] = row (p,p)
    {
        const float4* dsrc = (const float4*)(rowbase + pc * C2);
        #pragma unroll
        for (int c4 = 0; c4 < 8; ++c4) {
            float4 v = dsrc[c4];
            const float d0 = mp * v.x, d1 = mp * v.y, d2 = mp * v.z, d3 = mp * v.w;
            #pragma unroll
            for (int h = 0; h < HH; ++h)
                pre[h] += d0 * W16[(4*c4+0) * HH + h] + d1 * W16[(4*c4+1) * HH + h]
                        + d2 * W16[(4*c4+2) * HH + h] + d3 * W16[(4*c4+3) * HH + h];
        }
    }
    __syncthreads();   // sR complete
    // sum_tb[x2][c] = sum_t R[t][x2][c]
    for (int u = tid; u < 16 * C2; u += 256) {
        const int x2 = u >> 5, c = u & 31;
        float s = 0.f;
        #pragma unroll
        for (int tt = 0; tt < 16; ++tt) s += sR[tt * 16 + x2][c];
        s_stb[x2][c] = s;
    }
    __syncthreads();
    if (tid < C2) {
        float s = 0.f;
        #pragma unroll
        for (int x2 = 0; x2 < 16; ++x2) s += s_stb[x2][tid];
        s_sall[tid] = s;
    }
    __syncthreads();

    // ---- ST gather: branchless ----
    float ST[C2];
    #pragma unroll
    for (int c = 0; c < C2; ++c) ST[c] = 0.f;
    #pragma unroll
    for (int tp = 0; tp < 16; ++tp) {
        const int jt = s_nbi[tp];
        const int px = s_P[tp * 16 + x], py = s_P[tp * 16 + y];
        const float m = (px >= 0 && py >= 0) ? 1.f : 0.f;
        const int pxc = px >= 0 ? px : 0;
        const int pyc = py >= 0 ? py : 0;
        const float4* src = (const float4*)(F1 + (((size_t)jt * 16 + pxc) * 16 + pyc) * C2);
        #pragma unroll
        for (int c4 = 0; c4 < 8; ++c4) {
            float4 v = src[c4];
            ST[4*c4+0] = fmaf(m, v.x, ST[4*c4+0]);
            ST[4*c4+1] = fmaf(m, v.y, ST[4*c4+1]);
            ST[4*c4+2] = fmaf(m, v.z, ST[4*c4+2]);
            ST[4*c4+3] = fmaf(m, v.w, ST[4*c4+3]);
        }
    }
    // deferred matmuls: Wt2 (ST), Wtb (sum_tb), Wal (diag, branchless dxy)
    const float dxy = (x == y) ? 1.f : 0.f;
    #pragma unroll
    for (int c4 = 0; c4 < 8; ++c4) {
        const float4 sb4 = *(const float4*)&s_stb[x][4 * c4];
        const float4 sa4 = *(const float4*)&s_sall[4 * c4];
        const float sbv[4] = { sb4.x, sb4.y, sb4.z, sb4.w };
        const float sav[4] = { dxy * sa4.x, dxy * sa4.y, dxy * sa4.z, dxy * sa4.w };
        #pragma unroll
        for (int k = 0; k < 4; ++k) {
            const int c = 4 * c4 + k;
            const float st = ST[c], sb = sbv[k], sa = sav[k];
            #pragma unroll
            for (int h = 0; h < HH; ++h)
                pre[h] += st * Wt2[c * HH + h] + sb * Wtb[c * HH + h]
                        + sa * Wal[c * HH + h];
        }
    }

    // epilogue: bias, relu, dot fc_w, block reduce
    float local = 0.f;
    #pragma unroll
    for (int h = 0; h < HH; ++h) {
        float v = pre[h] + bias[h];
        v = v > 0.f ? v : 0.f;
        local += v * fcw[h];
    }
    #pragma unroll
    for (int off = 32; off > 0; off >>= 1) local += __shfl_down(local, off, 64);
    if ((tid & 63) == 0) s_red[tid >> 6] = local;
    __syncthreads();
    if (tid == 0) partials[i] = s_red[0] + s_red[1] + s_red[2] + s_red[3];
}

__global__ __launch_bounds__(256)
void ccn_finalize(const float* __restrict__ partials,
                  const float* __restrict__ fc_b,
                  float* __restrict__ out)
{
    float v = partials[threadIdx.x];
    #pragma unroll
    for (int off = 32; off > 0; off >>= 1) v += __shfl_down(v, off, 64);
    __shared__ float s_red[4];
    if ((threadIdx.x & 63) == 0) s_red[threadIdx.x >> 6] = v;
    __syncthreads();
    if (threadIdx.x == 0)
        out[0] = s_red[0] + s_red[1] + s_red[2] + s_red[3] + fc_b[0];
}

extern "C" void kernel_launch(void* const* d_in, const int* in_sizes, int n_in,
                              void* d_out, int out_size, void* d_ws, size_t ws_size,
                              hipStream_t stream) {
    const float* X    = (const float*)d_in[0];
    const int*   nbrs = (const int*)  d_in[1];
    const float* W1   = (const float*)d_in[2];
    const float* b1   = (const float*)d_in[3];
    const float* W2   = (const float*)d_in[4];
    const float* b2   = (const float*)d_in[5];
    const float* fc_w = (const float*)d_in[6];
    const float* fc_b = (const float*)d_in[7];
    float* outp = (float*)d_out;

    float* F1       = (float*)d_ws;                       // 8 MB
    float* partials = F1 + (size_t)NV * KN * KN * HH;     // 256
    float* E1       = partials + NV;                      // 6*512
    float* E2       = E1 + 6 * 16 * HH;                   // 6*1024

    ccn_prep<<<1, 256, 0, stream>>>(W1, W2, E1, E2);
    ccn_l1<<<NV, 256, 0, stream>>>(X, nbrs, E1, b1, F1);
    ccn_l2<<<NV, 256, 0, stream>>>(F1, nbrs, E2, b2, fc_w, partials);
    ccn_finalize<<<1, 256, 0, stream>>>(partials, fc_b, outp);
}

// Round 4
// 135.327 us; speedup vs baseline: 2.7375x; 1.8312x over previous
//
#include <hip/hip_runtime.h>

// CCN_2D on MI355X. N=256 vertices, K=16, C0=16, H=32.
// Facts (validated by exact passes R1-R3):
//  * CH rows one-hot => T_t[a][b][c] = Fin[j_t, P_t[a], P_t[b], c].
//  * A = I_16 collapses contract18 to 6 effective weight matrices.
//  * P_t[t] = -1 (no self-loops) => c17 / d_ttt terms vanish.
//  * Layer-1 input is broadcast of X => rank-1 closed form, no gathers.
// R3 lesson: uniform weight loads are NOT scalarized (s_load) by the compiler;
// per-weight VMEM/LDS load + dependent FMA serializes at 1 block/CU (~100 us).
// Fix: coalesced wave-load of weights + v_readlane broadcast (no memory in the
// FMA stream), cooperative matvecs for group-uniform coefficients, XCD-local
// block swizzle, transposed F1 layout for coalesced gathers.

constexpr int KN = 16, HH = 32, NV = 256, C2 = 32;

__device__ __forceinline__ float rlane(float v, int l) {
    return __int_as_float(__builtin_amdgcn_readlane(__float_as_int(v), l));
}

// ACC[h] += COEF(ci) * W[ci][h] for ci in [0, 8*NB), W flat row-major [c][32].
// Wave loads weights coalesced (float4/lane), broadcasts via readlane.
// Must be executed with all 64 lanes active (uniform control flow).
#define MM_RL(WPTR, NB, COEF_EXPR, ACC) do {                                   \
    _Pragma("unroll")                                                          \
    for (int B = 0; B < (NB); ++B) {                                           \
        const float4 w_ = ((const float4*)(WPTR))[B * 64 + lane];              \
        _Pragma("unroll")                                                      \
        for (int cc = 0; cc < 8; ++cc) {                                       \
            const int ci = B * 8 + cc;                                         \
            const float cf_ = (COEF_EXPR);                                     \
            _Pragma("unroll")                                                  \
            for (int h4 = 0; h4 < 8; ++h4) {                                   \
                const int src_ = 8 * cc + h4;                                  \
                (ACC)[4*h4+0] = fmaf(cf_, rlane(w_.x, src_), (ACC)[4*h4+0]);   \
                (ACC)[4*h4+1] = fmaf(cf_, rlane(w_.y, src_), (ACC)[4*h4+1]);   \
                (ACC)[4*h4+2] = fmaf(cf_, rlane(w_.z, src_), (ACC)[4*h4+2]);   \
                (ACC)[4*h4+3] = fmaf(cf_, rlane(w_.w, src_), (ACC)[4*h4+3]);   \
            }                                                                  \
        }                                                                      \
    }                                                                          \
} while (0)

// ---------------- prep: effective weights (6 blocks) ----------------
// E[0]=Wsb=16*W[g0]+W[g5]+16*sum(W[g6..g14]); E[1]=Wab=W[g1]; E[2]=W16=W[g15];
// E[3]=Wt2=16*W[g2]; E[4]=Wtb=W[g3]; E[5]=Wal=W[g4].
__global__ __launch_bounds__(256)
void ccn_prep(const float* __restrict__ W1, const float* __restrict__ W2,
              float* __restrict__ E1, float* __restrict__ E2)
{
    const int tid = threadIdx.x, blk = blockIdx.x;
    if (blk < 2) {
        const int CW = 16 * HH;  // 512
        const int u = blk * 256 + tid;
        float acc = 0.f;
        #pragma unroll
        for (int g = 6; g < 15; ++g) acc += W1[g * CW + u];
        E1[0 * CW + u] = 16.f * W1[0 * CW + u] + W1[5 * CW + u] + 16.f * acc;
        E1[1 * CW + u] = W1[1 * CW + u];
        E1[2 * CW + u] = W1[15 * CW + u];
        E1[3 * CW + u] = 16.f * W1[2 * CW + u];
        E1[4 * CW + u] = W1[3 * CW + u];
        E1[5 * CW + u] = W1[4 * CW + u];
    } else {
        const int CW = C2 * HH;  // 1024
        const int u = (blk - 2) * 256 + tid;
        float acc = 0.f;
        #pragma unroll
        for (int g = 6; g < 15; ++g) acc += W2[g * CW + u];
        E2[0 * CW + u] = 16.f * W2[0 * CW + u] + W2[5 * CW + u] + 16.f * acc;
        E2[1 * CW + u] = W2[1 * CW + u];
        E2[2 * CW + u] = W2[15 * CW + u];
        E2[3 * CW + u] = 16.f * W2[2 * CW + u];
        E2[4 * CW + u] = W2[3 * CW + u];
        E2[5 * CW + u] = W2[4 * CW + u];
    }
}

// ---------------- layer 1: rank-1 closed form ----------------
// pre = vy*V0 + V1 + vy*V2 + (Wt2^T Z2) + V3 + dxy*V4 where
// V0=(m*Y0)^T Wsb, V1=(m^2*Y0)^T Wab, V2=Y0^T W16, V3=Z4^T Wtb, V4=Z5^T Wal.
// Only the Z2 term is truly per-lane -> readlane matmul; rest cooperative.
__global__ __launch_bounds__(256)
void ccn_l1(const float* __restrict__ X, const int* __restrict__ nbrs,
            const float* __restrict__ E1, const float* __restrict__ bias,
            float* __restrict__ F1b)
{
    __shared__ int   s_nbi[16];
    __shared__ int   s_nbj[16][17];
    __shared__ int   s_P[16][16];
    __shared__ int   s_vm[16];
    __shared__ float s_m[16];
    __shared__ float sX[16][20];
    __shared__ float sV[16][164];   // 5 matvec results x 32 + pad

    const int tid = threadIdx.x;
    const int i   = ((blockIdx.x & 7) << 5) | (blockIdx.x >> 3);  // XCD swizzle
    const int t = tid >> 4, y = tid & 15;
    const int lane = tid & 63;

    if (tid < 16) s_nbi[tid] = nbrs[i * 16 + tid];
    __syncthreads();
    const int j = s_nbi[t];
    s_nbj[t][y] = nbrs[j * 16 + y];
    sX[t][y]    = X[j * 16 + y];
    __syncthreads();
    {
        const int tgt = s_nbi[y];
        int p = -1;
        #pragma unroll
        for (int q = 0; q < 16; ++q) if (s_nbj[t][q] == tgt) p = q;
        s_P[t][y] = p;
        unsigned long long bal = __ballot(p >= 0);
        if (y == 0) {
            int vm = (int)((bal >> ((t & 3) * 16)) & 0xFFFFull);
            s_vm[t] = vm;
            s_m[t]  = (float)__popc(vm);
        }
    }
    __syncthreads();

    const int x = t;
    float Y0[16];
    #pragma unroll
    for (int c4 = 0; c4 < 4; ++c4) {
        float4 v = *(const float4*)&sX[t][4 * c4];
        Y0[4*c4+0] = v.x; Y0[4*c4+1] = v.y; Y0[4*c4+2] = v.z; Y0[4*c4+3] = v.w;
    }
    float Z2[16], Z4[16], Z5[16];
    #pragma unroll
    for (int c = 0; c < 16; ++c) { Z2[c] = 0.f; Z4[c] = 0.f; Z5[c] = 0.f; }
    #pragma unroll
    for (int tp = 0; tp < 16; ++tp) {
        const int vm  = s_vm[tp];
        const float mt = s_m[tp];
        const float f2 = (float)((vm >> x) & (vm >> y) & 1);
        const float fb = ((vm >> x) & 1) ? mt : 0.f;
        const float f5 = mt * mt;
        #pragma unroll
        for (int c4 = 0; c4 < 4; ++c4) {
            float4 v = *(const float4*)&sX[tp][4 * c4];
            Z2[4*c4+0] = fmaf(f2, v.x, Z2[4*c4+0]);
            Z2[4*c4+1] = fmaf(f2, v.y, Z2[4*c4+1]);
            Z2[4*c4+2] = fmaf(f2, v.z, Z2[4*c4+2]);
            Z2[4*c4+3] = fmaf(f2, v.w, Z2[4*c4+3]);
            Z4[4*c4+0] = fmaf(fb, v.x, Z4[4*c4+0]);
            Z4[4*c4+1] = fmaf(fb, v.y, Z4[4*c4+1]);
            Z4[4*c4+2] = fmaf(fb, v.z, Z4[4*c4+2]);
            Z4[4*c4+3] = fmaf(fb, v.w, Z4[4*c4+3]);
            Z5[4*c4+0] = fmaf(f5, v.x, Z5[4*c4+0]);
            Z5[4*c4+1] = fmaf(f5, v.y, Z5[4*c4+1]);
            Z5[4*c4+2] = fmaf(f5, v.z, Z5[4*c4+2]);
            Z5[4*c4+3] = fmaf(f5, v.w, Z5[4*c4+3]);
        }
    }
    const float m = s_m[t];

    // cooperative: lane y computes h = 2y, 2y+1 for 5 matvecs of group t
    {
        float v0a = 0.f, v0b = 0.f, v1a = 0.f, v1b = 0.f, v2a = 0.f, v2b = 0.f;
        float v3a = 0.f, v3b = 0.f, v4a = 0.f, v4b = 0.f;
        const float2* Wsb = (const float2*)(E1 + 0 * 512);
        const float2* Wab = (const float2*)(E1 + 1 * 512);
        const float2* W16 = (const float2*)(E1 + 2 * 512);
        const float2* Wtb = (const float2*)(E1 + 4 * 512);
        const float2* Wal = (const float2*)(E1 + 5 * 512);
        #pragma unroll
        for (int c = 0; c < 16; ++c) {
            const float cf0 = m * Y0[c];
            const float cf1 = m * cf0;
            const float cf2 = Y0[c];
            const float cf3 = Z4[c];
            const float cf4 = Z5[c];
            const int idx = c * 16 + y;
            float2 w0 = Wsb[idx]; v0a = fmaf(cf0, w0.x, v0a); v0b = fmaf(cf0, w0.y, v0b);
            float2 w1 = Wab[idx]; v1a = fmaf(cf1, w1.x, v1a); v1b = fmaf(cf1, w1.y, v1b);
            float2 w2 = W16[idx]; v2a = fmaf(cf2, w2.x, v2a); v2b = fmaf(cf2, w2.y, v2b);
            float2 w3 = Wtb[idx]; v3a = fmaf(cf3, w3.x, v3a); v3b = fmaf(cf3, w3.y, v3b);
            float2 w4 = Wal[idx]; v4a = fmaf(cf4, w4.x, v4a); v4b = fmaf(cf4, w4.y, v4b);
        }
        *(float2*)&sV[t][0 * 32 + 2 * y] = make_float2(v0a, v0b);
        *(float2*)&sV[t][1 * 32 + 2 * y] = make_float2(v1a, v1b);
        *(float2*)&sV[t][2 * 32 + 2 * y] = make_float2(v2a, v2b);
        *(float2*)&sV[t][3 * 32 + 2 * y] = make_float2(v3a, v3b);
        *(float2*)&sV[t][4 * 32 + 2 * y] = make_float2(v4a, v4b);
    }

    float pre[HH];
    #pragma unroll
    for (int h = 0; h < HH; ++h) pre[h] = 0.f;
    MM_RL(E1 + 3 * 512, 2, Z2[ci], pre);   // Wt2^T Z2 (per-lane coef)

    __syncthreads();
    const float vy  = (s_P[t][y] >= 0) ? 1.f : 0.f;
    const float dxy = (x == y) ? 1.f : 0.f;
    #pragma unroll
    for (int h4 = 0; h4 < 8; ++h4) {
        const float4 V0 = *(const float4*)&sV[t][0 * 32 + 4 * h4];
        const float4 V1 = *(const float4*)&sV[t][1 * 32 + 4 * h4];
        const float4 V2 = *(const float4*)&sV[t][2 * 32 + 4 * h4];
        const float4 V3 = *(const float4*)&sV[t][3 * 32 + 4 * h4];
        const float4 V4 = *(const float4*)&sV[t][4 * 32 + 4 * h4];
        pre[4*h4+0] += vy * (V0.x + V2.x) + V1.x + V3.x + dxy * V4.x;
        pre[4*h4+1] += vy * (V0.y + V2.y) + V1.y + V3.y + dxy * V4.y;
        pre[4*h4+2] += vy * (V0.z + V2.z) + V1.z + V3.z + dxy * V4.z;
        pre[4*h4+3] += vy * (V0.w + V2.w) + V1.w + V3.w + dxy * V4.w;
    }
    // store TRANSPOSED layout: F1b[i][y][x][c] = F1[i][x][y][c]
    float4* dst = (float4*)(F1b + (((size_t)i * 16 + y) * 16 + x) * HH);
    #pragma unroll
    for (int h4 = 0; h4 < 8; ++h4) {
        float a_ = pre[4*h4+0] + bias[4*h4+0];
        float b_ = pre[4*h4+1] + bias[4*h4+1];
        float c_ = pre[4*h4+2] + bias[4*h4+2];
        float d_ = pre[4*h4+3] + bias[4*h4+3];
        dst[h4] = make_float4(a_ > 0.f ? a_ : 0.f, b_ > 0.f ? b_ : 0.f,
                              c_ > 0.f ? c_ : 0.f, d_ > 0.f ? d_ : 0.f);
    }
}

// ---------------- layer 2 ----------------
// F1b[j][q][p][c] holds F1[j][p][q][c].
__global__ __launch_bounds__(256)
void ccn_l2(const float* __restrict__ F1b, const int* __restrict__ nbrs,
            const float* __restrict__ E2, const float* __restrict__ bias,
            const float* __restrict__ fcw, float* __restrict__ partials)
{
    __shared__ float sR[256][36];      // R rows; reused for pp transpose
    __shared__ float s_stb[16][36];
    __shared__ float s_sall[C2];
    __shared__ float sV2[16][104];     // 3 cooperative matvecs x 32 + pad
    __shared__ int   s_nbi[16];
    __shared__ int   s_nbj[16][17];
    __shared__ int   s_P[256];
    __shared__ float s_red[4];

    const int tid = threadIdx.x;
    const int i   = ((blockIdx.x & 7) << 5) | (blockIdx.x >> 3);  // XCD swizzle
    const int t = tid >> 4, y = tid & 15;
    const int lane = tid & 63;

    if (tid < 16) s_nbi[tid] = nbrs[i * 16 + tid];
    __syncthreads();
    const int j = s_nbi[t];
    s_nbj[t][y] = nbrs[j * 16 + y];
    __syncthreads();
    {
        const int tgt = s_nbi[y];
        int p = -1;
        #pragma unroll
        for (int q = 0; q < 16; ++q) if (s_nbj[t][q] == tgt) p = q;
        s_P[t * 16 + y] = p;
    }
    __syncthreads();

    const int x = t;
    const int p = s_P[t * 16 + y];
    const float mp = (p >= 0) ? 1.f : 0.f;
    const int pc = p >= 0 ? p : 0;

    // ---- R gather (coalesced: q group-uniform, p lane-varying) ----
    float R[C2];
    #pragma unroll
    for (int c = 0; c < C2; ++c) R[c] = 0.f;
    #pragma unroll
    for (int b = 0; b < 16; ++b) {
        const int q = s_P[t * 16 + b];
        const float mm = (q >= 0) ? mp : 0.f;
        const int qc = q >= 0 ? q : 0;
        const float4* src = (const float4*)(F1b + (((size_t)j * 16 + qc) * 16 + pc) * C2);
        #pragma unroll
        for (int c4 = 0; c4 < 8; ++c4) {
            float4 v = src[c4];
            R[4*c4+0] = fmaf(mm, v.x, R[4*c4+0]);
            R[4*c4+1] = fmaf(mm, v.y, R[4*c4+1]);
            R[4*c4+2] = fmaf(mm, v.z, R[4*c4+2]);
            R[4*c4+3] = fmaf(mm, v.w, R[4*c4+3]);
        }
    }
    #pragma unroll
    for (int c4 = 0; c4 < 8; ++c4)
        *(float4*)&sR[t * 16 + y][4 * c4] =
            make_float4(R[4*c4+0], R[4*c4+1], R[4*c4+2], R[4*c4+3]);

    float pre[HH];
    #pragma unroll
    for (int h = 0; h < HH; ++h) pre[h] = 0.f;

    MM_RL(E2 + 0 * 1024, 4, R[ci], pre);   // Wsb^T R (per-lane)

    float sab[C2];
    #pragma unroll
    for (int c = 0; c < C2; ++c) {
        float s = R[c];
        s += __shfl_xor(s, 1);
        s += __shfl_xor(s, 2);
        s += __shfl_xor(s, 4);
        s += __shfl_xor(s, 8);
        sab[c] = s;
    }

    // diag D[c] = F1[j][p][p][c] = F1b[j][p][p][c]
    float D[C2];
    {
        const float4* dsrc = (const float4*)(F1b + (((size_t)j * 16 + pc) * 16 + pc) * C2);
        #pragma unroll
        for (int c4 = 0; c4 < 8; ++c4) {
            float4 v = dsrc[c4];
            D[4*c4+0] = mp * v.x; D[4*c4+1] = mp * v.y;
            D[4*c4+2] = mp * v.z; D[4*c4+3] = mp * v.w;
        }
    }
    MM_RL(E2 + 2 * 1024, 4, D[ci], pre);   // W16^T D (per-lane)

    __syncthreads();   // sR complete
    // sum_tb[x2][c] = sum_t R[t][x2][c]
    for (int u = tid; u < 16 * C2; u += 256) {
        const int x2 = u >> 5, c = u & 31;
        float s = 0.f;
        #pragma unroll
        for (int tt = 0; tt < 16; ++tt) s += sR[tt * 16 + x2][c];
        s_stb[x2][c] = s;
    }
    __syncthreads();
    if (tid < C2) {
        float s = 0.f;
        #pragma unroll
        for (int x2 = 0; x2 < 16; ++x2) s += s_stb[x2][tid];
        s_sall[tid] = s;
    }
    __syncthreads();

    // ---- cooperative matvecs: lane y computes h = 2y,2y+1 for group t ----
    {
        float va = 0.f, vb = 0.f, ta = 0.f, tb = 0.f, la = 0.f, lb = 0.f;
        const float2* Wab = (const float2*)(E2 + 1 * 1024);
        const float2* Wtb = (const float2*)(E2 + 4 * 1024);
        const float2* Wal = (const float2*)(E2 + 5 * 1024);
        #pragma unroll
        for (int c = 0; c < C2; ++c) {
            const float cfa = sab[c];
            const float cft = s_stb[t][c];
            const float cfl = s_sall[c];
            const int idx = c * 16 + y;
            float2 wa = Wab[idx]; va = fmaf(cfa, wa.x, va); vb = fmaf(cfa, wa.y, vb);
            float2 wt = Wtb[idx]; ta = fmaf(cft, wt.x, ta); tb = fmaf(cft, wt.y, tb);
            float2 wl = Wal[idx]; la = fmaf(cfl, wl.x, la); lb = fmaf(cfl, wl.y, lb);
        }
        *(float2*)&sV2[t][0 * 32 + 2 * y] = make_float2(va, vb);
        *(float2*)&sV2[t][1 * 32 + 2 * y] = make_float2(ta, tb);
        *(float2*)&sV2[t][2 * 32 + 2 * y] = make_float2(la, lb);
    }
    __syncthreads();
    {
        const float dxy = (x == y) ? 1.f : 0.f;
        #pragma unroll
        for (int h4 = 0; h4 < 8; ++h4) {
            const float4 Va = *(const float4*)&sV2[t][0 * 32 + 4 * h4];
            const float4 Vt = *(const float4*)&sV2[t][1 * 32 + 4 * h4];
            const float4 Vl = *(const float4*)&sV2[t][2 * 32 + 4 * h4];
            pre[4*h4+0] += Va.x + Vt.x + dxy * Vl.x;
            pre[4*h4+1] += Va.y + Vt.y + dxy * Vl.y;
            pre[4*h4+2] += Va.z + Vt.z + dxy * Vl.z;
            pre[4*h4+3] += Va.w + Vt.w + dxy * Vl.w;
        }
    }

    // ---- ST phase, remapped: group g = y', lane l = x' (coalesced) ----
    {
        const int g = tid >> 4, l = tid & 15;   // output (x=l, y=g)
        float ST[C2];
        #pragma unroll
        for (int c = 0; c < C2; ++c) ST[c] = 0.f;
        #pragma unroll 4
        for (int tp = 0; tp < 16; ++tp) {
            const int jt = s_nbi[tp];
            const int py = s_P[tp * 16 + g];    // group-uniform
            const int px = s_P[tp * 16 + l];    // lane-varying
            const float mm = (px >= 0 && py >= 0) ? 1.f : 0.f;
            const int pyc = py >= 0 ? py : 0;
            const int pxc = px >= 0 ? px : 0;
            const float4* src = (const float4*)(F1b + (((size_t)jt * 16 + pyc) * 16 + pxc) * C2);
            #pragma unroll
            for (int c4 = 0; c4 < 8; ++c4) {
                float4 v = src[c4];
                ST[4*c4+0] = fmaf(mm, v.x, ST[4*c4+0]);
                ST[4*c4+1] = fmaf(mm, v.y, ST[4*c4+1]);
                ST[4*c4+2] = fmaf(mm, v.z, ST[4*c4+2]);
                ST[4*c4+3] = fmaf(mm, v.w, ST[4*c4+3]);
            }
        }
        float pp[HH];
        #pragma unroll
        for (int h = 0; h < HH; ++h) pp[h] = 0.f;
        MM_RL(E2 + 3 * 1024, 4, ST[ci], pp);   // Wt2^T ST (per-lane)
        #pragma unroll
        for (int c4 = 0; c4 < 8; ++c4)
            *(float4*)&sR[g * 16 + l][4 * c4] =
                make_float4(pp[4*c4+0], pp[4*c4+1], pp[4*c4+2], pp[4*c4+3]);
    }
    __syncthreads();
    // owner (t,y) picks up its Wt2 contribution from thread (g=y, l=t)
    #pragma unroll
    for (int h4 = 0; h4 < 8; ++h4) {
        const float4 v = *(const float4*)&sR[y * 16 + t][4 * h4];
        pre[4*h4+0] += v.x; pre[4*h4+1] += v.y;
        pre[4*h4+2] += v.z; pre[4*h4+3] += v.w;
    }

    // ---- epilogue: bias, relu, dot fc_w, block reduce ----
    float local = 0.f;
    #pragma unroll
    for (int h = 0; h < HH; ++h) {
        float v = pre[h] + bias[h];
        v = v > 0.f ? v : 0.f;
        local += v * fcw[h];
    }
    #pragma unroll
    for (int off = 32; off > 0; off >>= 1) local += __shfl_down(local, off, 64);
    if ((tid & 63) == 0) s_red[tid >> 6] = local;
    __syncthreads();
    if (tid == 0) partials[i] = s_red[0] + s_red[1] + s_red[2] + s_red[3];
}

__global__ __launch_bounds__(256)
void ccn_finalize(const float* __restrict__ partials,
                  const float* __restrict__ fc_b,
                  float* __restrict__ out)
{
    float v = partials[threadIdx.x];
    #pragma unroll
    for (int off = 32; off > 0; off >>= 1) v += __shfl_down(v, off, 64);
    __shared__ float s_red[4];
    if ((threadIdx.x & 63) == 0) s_red[threadIdx.x >> 6] = v;
    __syncthreads();
    if (threadIdx.x == 0)
        out[0] = s_red[0] + s_red[1] + s_red[2] + s_red[3] + fc_b[0];
}

extern "C" void kernel_launch(void* const* d_in, const int* in_sizes, int n_in,
                              void* d_out, int out_size, void* d_ws, size_t ws_size,
                              hipStream_t stream) {
    const float* X    = (const float*)d_in[0];
    const int*   nbrs = (const int*)  d_in[1];
    const float* W1   = (const float*)d_in[2];
    const float* b1   = (const float*)d_in[3];
    const float* W2   = (const float*)d_in[4];
    const float* b2   = (const float*)d_in[5];
    const float* fc_w = (const float*)d_in[6];
    const float* fc_b = (const float*)d_in[7];
    float* outp = (float*)d_out;

    float* F1b      = (float*)d_ws;                       // 8 MB
    float* partials = F1b + (size_t)NV * KN * KN * HH;    // 256
    float* E1       = partials + NV;                      // 6*512
    float* E2       = E1 + 6 * 16 * HH;                   // 6*1024

    ccn_prep<<<6, 256, 0, stream>>>(W1, W2, E1, E2);
    ccn_l1<<<NV, 256, 0, stream>>>(X, nbrs, E1, b1, F1b);
    ccn_l2<<<NV, 256, 0, stream>>>(F1b, nbrs, E2, b2, fc_w, partials);
    ccn_finalize<<<1, 256, 0, stream>>>(partials, fc_b, outp);
}

// Round 5
// 122.930 us; speedup vs baseline: 3.0136x; 1.1009x over previous
//
#include <hip/hip_runtime.h>

// CCN_2D on MI355X. N=256 vertices, K=16, C0=16, H=32.
// Facts (validated by exact passes R1-R4):
//  * CH rows one-hot => T_t[a][b][c] = Fin[j_t, P_t[a], P_t[b], c].
//  * A = I_16 collapses contract18 to 6 effective weight matrices.
//  * P_t[t] = -1 (no self-loops) => c17 / d_ttt terms vanish.
//  * Layer-1 input is broadcast of X => rank-1 closed form, no gathers.
// R4 lesson: 256-thread blocks = 1 wave/SIMD = zero latency hiding; 4 launches
// cost ~half the wall clock. This version: 2 launches, 512-thread blocks with
// phase-parallel halves (A: R-phase; B: weight prep + ST-phase), all weights
// in LDS, readlane-broadcast matmuls, atomicAdd finish.

constexpr int KN = 16, HH = 32, NV = 256, C2 = 32;

__device__ __forceinline__ float rlane(float v, int l) {
    return __int_as_float(__builtin_amdgcn_readlane(__float_as_int(v), l));
}

// ACC[h] += COEF(ci) * W[ci][h], ci in [0, 8*NB), W row-major [c][32] (LDS ok).
// Wave-coalesced weight load (float4/lane) + readlane broadcast. All 64 lanes
// of the executing wave must be active.
#define MM_RL(WPTR, NB, COEF_EXPR, ACC) do {                                   \
    _Pragma("unroll")                                                          \
    for (int B = 0; B < (NB); ++B) {                                           \
        const float4 w_ = ((const float4*)(WPTR))[B * 64 + lane];              \
        _Pragma("unroll")                                                      \
        for (int cc = 0; cc < 8; ++cc) {                                       \
            const int ci = B * 8 + cc;                                         \
            const float cf_ = (COEF_EXPR);                                     \
            _Pragma("unroll")                                                  \
            for (int h4 = 0; h4 < 8; ++h4) {                                   \
                const int src_ = 8 * cc + h4;                                  \
                (ACC)[4*h4+0] = fmaf(cf_, rlane(w_.x, src_), (ACC)[4*h4+0]);   \
                (ACC)[4*h4+1] = fmaf(cf_, rlane(w_.y, src_), (ACC)[4*h4+1]);   \
                (ACC)[4*h4+2] = fmaf(cf_, rlane(w_.z, src_), (ACC)[4*h4+2]);   \
                (ACC)[4*h4+3] = fmaf(cf_, rlane(w_.w, src_), (ACC)[4*h4+3]);   \
            }                                                                  \
        }                                                                      \
    }                                                                          \
} while (0)

// ---------------- layer 1 ----------------
// E1 slices (512 floats each): 0:Wsb 1:Wab 2:W16 3:Wt2 4:Wtb 5:Wal
// pre = vy*(m*Y0·Wsb) + (m^2*Y0)·Wab + vy*(Y0·W16) + Z2·Wt2 + Z4·Wtb + dxy*Z5·Wal
__global__ __launch_bounds__(512)
void ccn_l1(const float* __restrict__ X, const int* __restrict__ nbrs,
            const float* __restrict__ W1, const float* __restrict__ bias,
            float* __restrict__ F1b, float* __restrict__ outz)
{
    __shared__ float sE1[6 * 512];     // 12 KB
    __shared__ float sPP[256 * 36];    // 36 KB (half-B Z2*Wt2 results)
    __shared__ float sX[16][20];
    __shared__ float sV[16][164];      // 5 matvec results x 32 per group
    __shared__ int   s_nbi[16];
    __shared__ int   s_nbj[16][17];
    __shared__ int   s_P[16][16];
    __shared__ int   s_vm[16];
    __shared__ float s_m[16];

    const int tid  = threadIdx.x;
    const int i    = ((blockIdx.x & 7) << 5) | (blockIdx.x >> 3);  // XCD swizzle
    const int lane = tid & 63;

    if (blockIdx.x == 0 && tid == 0) outz[0] = 0.f;   // zero accumulator for l2
    if (tid < 16) s_nbi[tid] = nbrs[i * 16 + tid];
    __syncthreads();  // B0

    if (tid < 256) {
        const int t = tid >> 4, y = tid & 15;
        const int j = s_nbi[t];
        s_nbj[t][y] = nbrs[j * 16 + y];
        sX[t][y]    = X[j * 16 + y];
    } else {
        const int u = tid - 256;       // E1 entries 0..255
        float acc = 0.f;
        #pragma unroll
        for (int g = 6; g < 15; ++g) acc += W1[g * 512 + u];
        sE1[u]        = 16.f * W1[u] + W1[5 * 512 + u] + 16.f * acc;
        sE1[512 + u]  = W1[512 + u];
        sE1[1024 + u] = W1[15 * 512 + u];
        sE1[1536 + u] = 16.f * W1[2 * 512 + u];
        sE1[2048 + u] = W1[3 * 512 + u];
        sE1[2560 + u] = W1[4 * 512 + u];
    }
    __syncthreads();  // B1

    if (tid < 256) {
        const int t = tid >> 4, y = tid & 15;
        const int tgt = s_nbi[y];
        int p = -1;
        #pragma unroll
        for (int q = 0; q < 16; ++q) if (s_nbj[t][q] == tgt) p = q;
        s_P[t][y] = p;
        unsigned long long bal = __ballot(p >= 0);
        if (y == 0) {
            int vm = (int)((bal >> ((t & 3) * 16)) & 0xFFFFull);
            s_vm[t] = vm;
            s_m[t]  = (float)__popc(vm);
        }
    } else {
        const int u = tid;             // E1 entries 256..511
        float acc = 0.f;
        #pragma unroll
        for (int g = 6; g < 15; ++g) acc += W1[g * 512 + u];
        sE1[u]        = 16.f * W1[u] + W1[5 * 512 + u] + 16.f * acc;
        sE1[512 + u]  = W1[512 + u];
        sE1[1024 + u] = W1[15 * 512 + u];
        sE1[1536 + u] = 16.f * W1[2 * 512 + u];
        sE1[2048 + u] = W1[3 * 512 + u];
        sE1[2560 + u] = W1[4 * 512 + u];
    }
    __syncthreads();  // B2

    if (tid < 256) {
        // ---- half A: Z4/Z5 + 5 cooperative matvecs (lane y -> h=2y,2y+1) ----
        const int t = tid >> 4, y = tid & 15, x = t;
        float Y0[16];
        #pragma unroll
        for (int c4 = 0; c4 < 4; ++c4) {
            float4 v = *(const float4*)&sX[t][4 * c4];
            Y0[4*c4+0] = v.x; Y0[4*c4+1] = v.y; Y0[4*c4+2] = v.z; Y0[4*c4+3] = v.w;
        }
        float Z4[16], Z5[16];
        #pragma unroll
        for (int c = 0; c < 16; ++c) { Z4[c] = 0.f; Z5[c] = 0.f; }
        #pragma unroll
        for (int tp = 0; tp < 16; ++tp) {
            const int vm = s_vm[tp];
            const float mt = s_m[tp];
            const float fb = ((vm >> x) & 1) ? mt : 0.f;
            const float f5 = mt * mt;
            #pragma unroll
            for (int c4 = 0; c4 < 4; ++c4) {
                float4 v = *(const float4*)&sX[tp][4 * c4];
                Z4[4*c4+0] = fmaf(fb, v.x, Z4[4*c4+0]);
                Z4[4*c4+1] = fmaf(fb, v.y, Z4[4*c4+1]);
                Z4[4*c4+2] = fmaf(fb, v.z, Z4[4*c4+2]);
                Z4[4*c4+3] = fmaf(fb, v.w, Z4[4*c4+3]);
                Z5[4*c4+0] = fmaf(f5, v.x, Z5[4*c4+0]);
                Z5[4*c4+1] = fmaf(f5, v.y, Z5[4*c4+1]);
                Z5[4*c4+2] = fmaf(f5, v.z, Z5[4*c4+2]);
                Z5[4*c4+3] = fmaf(f5, v.w, Z5[4*c4+3]);
            }
        }
        const float m = s_m[t];
        float v0a=0.f,v0b=0.f,v1a=0.f,v1b=0.f,v2a=0.f,v2b=0.f;
        float v3a=0.f,v3b=0.f,v4a=0.f,v4b=0.f;
        const float2* Wsb = (const float2*)(sE1 + 0 * 512);
        const float2* Wab = (const float2*)(sE1 + 1 * 512);
        const float2* W16 = (const float2*)(sE1 + 2 * 512);
        const float2* Wtb = (const float2*)(sE1 + 4 * 512);
        const float2* Wal = (const float2*)(sE1 + 5 * 512);
        #pragma unroll
        for (int c = 0; c < 16; ++c) {
            const float cf0 = m * Y0[c];
            const float cf1 = m * cf0;
            const float cf2 = Y0[c];
            const float cf3 = Z4[c];
            const float cf4 = Z5[c];
            const int idx = c * 16 + y;
            float2 w0 = Wsb[idx]; v0a = fmaf(cf0, w0.x, v0a); v0b = fmaf(cf0, w0.y, v0b);
            float2 w1 = Wab[idx]; v1a = fmaf(cf1, w1.x, v1a); v1b = fmaf(cf1, w1.y, v1b);
            float2 w2 = W16[idx]; v2a = fmaf(cf2, w2.x, v2a); v2b = fmaf(cf2, w2.y, v2b);
            float2 w3 = Wtb[idx]; v3a = fmaf(cf3, w3.x, v3a); v3b = fmaf(cf3, w3.y, v3b);
            float2 w4 = Wal[idx]; v4a = fmaf(cf4, w4.x, v4a); v4b = fmaf(cf4, w4.y, v4b);
        }
        *(float2*)&sV[t][0 * 32 + 2 * y] = make_float2(v0a, v0b);
        *(float2*)&sV[t][1 * 32 + 2 * y] = make_float2(v1a, v1b);
        *(float2*)&sV[t][2 * 32 + 2 * y] = make_float2(v2a, v2b);
        *(float2*)&sV[t][3 * 32 + 2 * y] = make_float2(v3a, v3b);
        *(float2*)&sV[t][4 * 32 + 2 * y] = make_float2(v4a, v4b);
    } else {
        // ---- half B: Z2 + Wt2 readlane-matmul ----
        const int w = tid - 256;
        const int t = w >> 4, y = w & 15, x = t;
        float Z2[16];
        #pragma unroll
        for (int c = 0; c < 16; ++c) Z2[c] = 0.f;
        #pragma unroll
        for (int tp = 0; tp < 16; ++tp) {
            const int vm = s_vm[tp];
            const float f2 = (float)((vm >> x) & (vm >> y) & 1);
            #pragma unroll
            for (int c4 = 0; c4 < 4; ++c4) {
                float4 v = *(const float4*)&sX[tp][4 * c4];
                Z2[4*c4+0] = fmaf(f2, v.x, Z2[4*c4+0]);
                Z2[4*c4+1] = fmaf(f2, v.y, Z2[4*c4+1]);
                Z2[4*c4+2] = fmaf(f2, v.z, Z2[4*c4+2]);
                Z2[4*c4+3] = fmaf(f2, v.w, Z2[4*c4+3]);
            }
        }
        float pp[HH];
        #pragma unroll
        for (int h = 0; h < HH; ++h) pp[h] = 0.f;
        MM_RL(sE1 + 3 * 512, 2, Z2[ci], pp);
        float* dst = &sPP[(t * 16 + y) * 36];
        #pragma unroll
        for (int h4 = 0; h4 < 8; ++h4)
            *(float4*)&dst[4 * h4] = make_float4(pp[4*h4], pp[4*h4+1], pp[4*h4+2], pp[4*h4+3]);
    }
    __syncthreads();  // B3

    if (tid < 256) {
        const int t = tid >> 4, y = tid & 15, x = t;
        const float vy  = (s_P[t][y] >= 0) ? 1.f : 0.f;
        const float dxy = (x == y) ? 1.f : 0.f;
        const float* pp = &sPP[(t * 16 + y) * 36];
        float4* dst = (float4*)(F1b + (((size_t)i * 16 + y) * 16 + x) * HH);
        #pragma unroll
        for (int h4 = 0; h4 < 8; ++h4) {
            const float4 V0 = *(const float4*)&sV[t][0 * 32 + 4 * h4];
            const float4 V1 = *(const float4*)&sV[t][1 * 32 + 4 * h4];
            const float4 V2 = *(const float4*)&sV[t][2 * 32 + 4 * h4];
            const float4 V3 = *(const float4*)&sV[t][3 * 32 + 4 * h4];
            const float4 V4 = *(const float4*)&sV[t][4 * 32 + 4 * h4];
            const float4 PP = *(const float4*)&pp[4 * h4];
            float a_ = vy*(V0.x+V2.x) + V1.x + V3.x + dxy*V4.x + PP.x + bias[4*h4+0];
            float b_ = vy*(V0.y+V2.y) + V1.y + V3.y + dxy*V4.y + PP.y + bias[4*h4+1];
            float c_ = vy*(V0.z+V2.z) + V1.z + V3.z + dxy*V4.z + PP.z + bias[4*h4+2];
            float d_ = vy*(V0.w+V2.w) + V1.w + V3.w + dxy*V4.w + PP.w + bias[4*h4+3];
            dst[h4] = make_float4(a_ > 0.f ? a_ : 0.f, b_ > 0.f ? b_ : 0.f,
                                  c_ > 0.f ? c_ : 0.f, d_ > 0.f ? d_ : 0.f);
        }
    }
}

// ---------------- layer 2 ----------------
// E2 slices (1024 floats each): 0:Wsb 1:Wab 2:W16 3:Wt2 4:Wtb 5:Wal
// F1b[j][q][p][c] = F1[j][p][q][c].
__global__ __launch_bounds__(512)
void ccn_l2(const float* __restrict__ F1b, const int* __restrict__ nbrs,
            const float* __restrict__ W2, const float* __restrict__ bias,
            const float* __restrict__ fcw, const float* __restrict__ fcb,
            float* __restrict__ out)
{
    __shared__ float sE2[6 * 1024];    // 24 KB
    __shared__ float sRpp[256 * 36];   // 36 KB: R rows, then half-B pp results
    __shared__ float s_stb[16 * 33];
    __shared__ float s_sall[C2];
    __shared__ int   s_nbi[16];
    __shared__ int   s_PQ[16 * 17];    // nbj, then overwritten with P (wave-local)
    __shared__ float s_red[4];

    const int tid  = threadIdx.x;
    const int i    = ((blockIdx.x & 7) << 5) | (blockIdx.x >> 3);  // XCD swizzle
    const int lane = tid & 63;

    if (tid < 16) s_nbi[tid] = nbrs[i * 16 + tid];
    __syncthreads();  // B0

    if (tid < 256) {
        const int t = tid >> 4, y = tid & 15;
        const int j = s_nbi[t];
        s_PQ[t * 17 + y] = nbrs[j * 16 + y];
    } else {
        const int w = tid - 256;
        #pragma unroll
        for (int k = 0; k < 2; ++k) {
            const int u = w + k * 256;          // E2 entries 0..511
            float acc = 0.f;
            #pragma unroll
            for (int g = 6; g < 15; ++g) acc += W2[g * 1024 + u];
            sE2[u]        = 16.f * W2[u] + W2[5 * 1024 + u] + 16.f * acc;
            sE2[1024 + u] = W2[1024 + u];
            sE2[2048 + u] = W2[15 * 1024 + u];
            sE2[3072 + u] = 16.f * W2[2 * 1024 + u];
            sE2[4096 + u] = W2[3 * 1024 + u];
            sE2[5120 + u] = W2[4 * 1024 + u];
        }
    }
    __syncthreads();  // B1

    if (tid < 256) {
        const int t = tid >> 4, y = tid & 15;
        const int tgt = s_nbi[y];
        int p = -1;
        #pragma unroll
        for (int q = 0; q < 16; ++q) if (s_PQ[t * 17 + q] == tgt) p = q;
        s_PQ[t * 17 + y] = p;   // overwrite: reads above precede write (wave lockstep)
    } else {
        const int w = tid - 256;
        #pragma unroll
        for (int k = 2; k < 4; ++k) {
            const int u = w + k * 256;          // E2 entries 512..1023
            float acc = 0.f;
            #pragma unroll
            for (int g = 6; g < 15; ++g) acc += W2[g * 1024 + u];
            sE2[u]        = 16.f * W2[u] + W2[5 * 1024 + u] + 16.f * acc;
            sE2[1024 + u] = W2[1024 + u];
            sE2[2048 + u] = W2[15 * 1024 + u];
            sE2[3072 + u] = 16.f * W2[2 * 1024 + u];
            sE2[4096 + u] = W2[3 * 1024 + u];
            sE2[5120 + u] = W2[4 * 1024 + u];
        }
    }
    __syncthreads();  // B2

    float pre[HH];
    float sab[C2];
    float pp[HH];

    if (tid < 256) {
        // ---- half A: R gather + Wsb/W16 readlane matmuls ----
        const int t = tid >> 4, y = tid & 15;
        const int j = s_nbi[t];
        const int p = s_PQ[t * 17 + y];
        const float mp = (p >= 0) ? 1.f : 0.f;
        const int pc = p >= 0 ? p : 0;

        float R[C2];
        #pragma unroll
        for (int c = 0; c < C2; ++c) R[c] = 0.f;
        #pragma unroll
        for (int b = 0; b < 16; ++b) {
            const int q = s_PQ[t * 17 + b];
            const float mm = (q >= 0) ? mp : 0.f;
            const int qc = q >= 0 ? q : 0;
            const float4* src = (const float4*)(F1b + (((size_t)j * 16 + qc) * 16 + pc) * C2);
            #pragma unroll
            for (int c4 = 0; c4 < 8; ++c4) {
                float4 v = src[c4];
                R[4*c4+0] = fmaf(mm, v.x, R[4*c4+0]);
                R[4*c4+1] = fmaf(mm, v.y, R[4*c4+1]);
                R[4*c4+2] = fmaf(mm, v.z, R[4*c4+2]);
                R[4*c4+3] = fmaf(mm, v.w, R[4*c4+3]);
            }
        }
        #pragma unroll
        for (int c4 = 0; c4 < 8; ++c4)
            *(float4*)&sRpp[(t * 16 + y) * 36 + 4 * c4] =
                make_float4(R[4*c4+0], R[4*c4+1], R[4*c4+2], R[4*c4+3]);

        #pragma unroll
        for (int h = 0; h < HH; ++h) pre[h] = 0.f;
        MM_RL(sE2 + 0 * 1024, 4, R[ci], pre);          // Wsb^T R

        #pragma unroll
        for (int c = 0; c < C2; ++c) {
            float s = R[c];
            s += __shfl_xor(s, 1);
            s += __shfl_xor(s, 2);
            s += __shfl_xor(s, 4);
            s += __shfl_xor(s, 8);
            sab[c] = s;
        }

        float D[C2];
        {
            const float4* dsrc = (const float4*)(F1b + (((size_t)j * 16 + pc) * 16 + pc) * C2);
            #pragma unroll
            for (int c4 = 0; c4 < 8; ++c4) {
                float4 v = dsrc[c4];
                D[4*c4+0] = mp * v.x; D[4*c4+1] = mp * v.y;
                D[4*c4+2] = mp * v.z; D[4*c4+3] = mp * v.w;
            }
        }
        MM_RL(sE2 + 2 * 1024, 4, D[ci], pre);          // W16^T D
    } else {
        // ---- half B: ST gather + Wt2 readlane matmul ----
        const int w = tid - 256;
        const int g = w >> 4, l = w & 15;              // output (x=l, y=g)
        float ST[C2];
        #pragma unroll
        for (int c = 0; c < C2; ++c) ST[c] = 0.f;
        #pragma unroll
        for (int tp = 0; tp < 16; ++tp) {
            const int jt = s_nbi[tp];
            const int py = s_PQ[tp * 17 + g];          // group-uniform
            const int px = s_PQ[tp * 17 + l];          // lane-varying
            const float mm = (px >= 0 && py >= 0) ? 1.f : 0.f;
            const int pyc = py >= 0 ? py : 0;
            const int pxc = px >= 0 ? px : 0;
            const float4* src = (const float4*)(F1b + (((size_t)jt * 16 + pyc) * 16 + pxc) * C2);
            #pragma unroll
            for (int c4 = 0; c4 < 8; ++c4) {
                float4 v = src[c4];
                ST[4*c4+0] = fmaf(mm, v.x, ST[4*c4+0]);
                ST[4*c4+1] = fmaf(mm, v.y, ST[4*c4+1]);
                ST[4*c4+2] = fmaf(mm, v.z, ST[4*c4+2]);
                ST[4*c4+3] = fmaf(mm, v.w, ST[4*c4+3]);
            }
        }
        #pragma unroll
        for (int h = 0; h < HH; ++h) pp[h] = 0.f;
        MM_RL(sE2 + 3 * 1024, 4, ST[ci], pp);          // Wt2^T ST
    }
    __syncthreads();  // B3  (sR rows complete)

    if (tid < 256) {
        // stb[x2][c] = sum_t R[t][x2][c]
        #pragma unroll
        for (int k = 0; k < 2; ++k) {
            const int x2 = (tid >> 5) + 8 * k;
            const int c = tid & 31;
            float s = 0.f;
            #pragma unroll
            for (int tt = 0; tt < 16; ++tt) s += sRpp[(tt * 16 + x2) * 36 + c];
            s_stb[x2 * 33 + c] = s;
        }
    }
    __syncthreads();  // B4  (stb complete; sR now dead)

    if (tid < 256) {
        if (tid < 32) {
            float s = 0.f;
            #pragma unroll
            for (int x2 = 0; x2 < 16; ++x2) s += s_stb[x2 * 33 + tid];
            s_sall[tid] = s;
        }
    } else {
        // half B parks its pp into the dead sR buffer at row x*16+y = l*16+g
        const int w = tid - 256;
        const int g = w >> 4, l = w & 15;
        float* dst = &sRpp[(l * 16 + g) * 36];
        #pragma unroll
        for (int h4 = 0; h4 < 8; ++h4)
            *(float4*)&dst[4 * h4] = make_float4(pp[4*h4], pp[4*h4+1], pp[4*h4+2], pp[4*h4+3]);
    }
    __syncthreads();  // B5

    if (tid < 256) {
        const int t = tid >> 4, y = tid & 15, x = t;
        const float dxy = (x == y) ? 1.f : 0.f;
        // cooperative matvecs Wab/Wtb/Wal (lane y -> h=2y,2y+1), combine via shfl
        float S0 = 0.f, S1 = 0.f, L0 = 0.f, L1 = 0.f;
        {
            const float2* Wab = (const float2*)(sE2 + 1 * 1024);
            const float2* Wtb = (const float2*)(sE2 + 4 * 1024);
            const float2* Wal = (const float2*)(sE2 + 5 * 1024);
            #pragma unroll
            for (int c = 0; c < C2; ++c) {
                const float cfa = sab[c];
                const float cft = s_stb[t * 33 + c];
                const float cfl = s_sall[c];
                const int idx = c * 16 + y;
                float2 wa = Wab[idx]; S0 = fmaf(cfa, wa.x, S0); S1 = fmaf(cfa, wa.y, S1);
                float2 wt = Wtb[idx]; S0 = fmaf(cft, wt.x, S0); S1 = fmaf(cft, wt.y, S1);
                float2 wl = Wal[idx]; L0 = fmaf(cfl, wl.x, L0); L1 = fmaf(cfl, wl.y, L1);
            }
        }
        const int gbase = (t & 3) * 16;
        #pragma unroll
        for (int h = 0; h < HH; ++h) {
            const int src = gbase + (h >> 1);
            const float sv = (h & 1) ? S1 : S0;
            const float lv = (h & 1) ? L1 : L0;
            pre[h] += __shfl(sv, src, 64) + dxy * __shfl(lv, src, 64);
        }
        // pick up half B's Wt2 contribution (row t*16+y)
        {
            const float* ppr = &sRpp[(t * 16 + y) * 36];
            #pragma unroll
            for (int h4 = 0; h4 < 8; ++h4) {
                const float4 v = *(const float4*)&ppr[4 * h4];
                pre[4*h4+0] += v.x; pre[4*h4+1] += v.y;
                pre[4*h4+2] += v.z; pre[4*h4+3] += v.w;
            }
        }
        // epilogue: bias, relu, dot fcw, wave reduce
        float local = 0.f;
        #pragma unroll
        for (int h = 0; h < HH; ++h) {
            float v = pre[h] + bias[h];
            v = v > 0.f ? v : 0.f;
            local += v * fcw[h];
        }
        #pragma unroll
        for (int off = 32; off > 0; off >>= 1) local += __shfl_down(local, off, 64);
        if (lane == 0) s_red[tid >> 6] = local;
    }
    __syncthreads();  // B6
    if (tid == 0) {
        const float v = s_red[0] + s_red[1] + s_red[2] + s_red[3]
                      + fcb[0] * (1.f / 256.f);
        atomicAdd(out, v);
    }
}

extern "C" void kernel_launch(void* const* d_in, const int* in_sizes, int n_in,
                              void* d_out, int out_size, void* d_ws, size_t ws_size,
                              hipStream_t stream) {
    const float* X    = (const float*)d_in[0];
    const int*   nbrs = (const int*)  d_in[1];
    const float* W1   = (const float*)d_in[2];
    const float* b1   = (const float*)d_in[3];
    const float* W2   = (const float*)d_in[4];
    const float* b2   = (const float*)d_in[5];
    const float* fc_w = (const float*)d_in[6];
    const float* fc_b = (const float*)d_in[7];
    float* outp = (float*)d_out;

    float* F1b = (float*)d_ws;   // 256*16*16*32 floats = 8 MB

    ccn_l1<<<NV, 512, 0, stream>>>(X, nbrs, W1, b1, F1b, outp);
    ccn_l2<<<NV, 512, 0, stream>>>(F1b, nbrs, W2, b2, fc_w, fc_b, outp);
}

// Round 6
// 107.743 us; speedup vs baseline: 3.4384x; 1.1410x over previous
//
#include <hip/hip_runtime.h>

// CCN_2D on MI355X. N=256 vertices, K=16, C0=16, H=32.
// Facts (validated by exact passes R1-R5):
//  * CH rows one-hot => T_t[a][b][c] = Fin[j_t, P_t[a], P_t[b], c].
//  * A = I_16 collapses contract18 to 6 effective weight matrices.
//  * P_t[t] = -1 (no self-loops) => c17 / d_ttt terms vanish.
//  * Layer-1 input is broadcast of X => rank-1 closed form, no gathers.
// R5 lesson: l2 is L1-transaction bound: row-major F1 rows give 64
// quarter-used lines per gather instruction. Fix: channel-interleaved
// layout F1c[j][q][c4][p][4] so the lane-varying index p has 16 B stride ->
// 16 fully-used lines per instruction (4x fewer L1 transactions).

constexpr int KN = 16, HH = 32, NV = 256, C2 = 32;

__device__ __forceinline__ float rlane(float v, int l) {
    return __int_as_float(__builtin_amdgcn_readlane(__float_as_int(v), l));
}

// ACC[h] += COEF(ci) * W[ci][h], ci in [0, 8*NB), W row-major [c][32] (LDS ok).
// Wave-coalesced weight load (float4/lane) + readlane broadcast. All 64 lanes
// of the executing wave must be active.
#define MM_RL(WPTR, NB, COEF_EXPR, ACC) do {                                   \
    _Pragma("unroll")                                                          \
    for (int B = 0; B < (NB); ++B) {                                           \
        const float4 w_ = ((const float4*)(WPTR))[B * 64 + lane];              \
        _Pragma("unroll")                                                      \
        for (int cc = 0; cc < 8; ++cc) {                                       \
            const int ci = B * 8 + cc;                                         \
            const float cf_ = (COEF_EXPR);                                     \
            _Pragma("unroll")                                                  \
            for (int h4 = 0; h4 < 8; ++h4) {                                   \
                const int src_ = 8 * cc + h4;                                  \
                (ACC)[4*h4+0] = fmaf(cf_, rlane(w_.x, src_), (ACC)[4*h4+0]);   \
                (ACC)[4*h4+1] = fmaf(cf_, rlane(w_.y, src_), (ACC)[4*h4+1]);   \
                (ACC)[4*h4+2] = fmaf(cf_, rlane(w_.z, src_), (ACC)[4*h4+2]);   \
                (ACC)[4*h4+3] = fmaf(cf_, rlane(w_.w, src_), (ACC)[4*h4+3]);   \
            }                                                                  \
        }                                                                      \
    }                                                                          \
} while (0)

// ---------------- layer 1 ----------------
// E1 slices (512 floats each): 0:Wsb 1:Wab 2:W16 3:Wt2 4:Wtb 5:Wal
// pre = vy*(m*Y0.Wsb) + (m^2*Y0).Wab + vy*(Y0.W16) + Z2.Wt2 + Z4.Wtb + dxy*Z5.Wal
// Output layout (float4 chunks): F1c chunk index = (i*16+q)*128 + c4*16 + p,
// holding channels c4*4..c4*4+3 of logical F1[i][p][q][:]. (q,p) = (y,x).
__global__ __launch_bounds__(512)
void ccn_l1(const float* __restrict__ X, const int* __restrict__ nbrs,
            const float* __restrict__ W1, const float* __restrict__ bias,
            float* __restrict__ F1c, float* __restrict__ outz)
{
    __shared__ float sE1[6 * 512];     // 12 KB
    __shared__ float sPP[256 * 36];    // 36 KB (half-B results, then park)
    __shared__ float sX[16][20];
    __shared__ float sV[16][164];      // 5 matvec results x 32 per group
    __shared__ int   s_nbi[16];
    __shared__ int   s_nbj[16][17];
    __shared__ int   s_P[16][16];
    __shared__ int   s_vm[16];
    __shared__ float s_m[16];

    const int tid  = threadIdx.x;
    const int i    = ((blockIdx.x & 7) << 5) | (blockIdx.x >> 3);  // XCD swizzle
    const int lane = tid & 63;

    if (blockIdx.x == 0 && tid == 0) outz[0] = 0.f;   // zero accumulator for l2
    if (tid < 16) s_nbi[tid] = nbrs[i * 16 + tid];
    __syncthreads();  // B0

    if (tid < 256) {
        const int t = tid >> 4, y = tid & 15;
        const int j = s_nbi[t];
        s_nbj[t][y] = nbrs[j * 16 + y];
        sX[t][y]    = X[j * 16 + y];
    } else {
        const int u = tid - 256;       // E1 entries 0..255
        float acc = 0.f;
        #pragma unroll
        for (int g = 6; g < 15; ++g) acc += W1[g * 512 + u];
        sE1[u]        = 16.f * W1[u] + W1[5 * 512 + u] + 16.f * acc;
        sE1[512 + u]  = W1[512 + u];
        sE1[1024 + u] = W1[15 * 512 + u];
        sE1[1536 + u] = 16.f * W1[2 * 512 + u];
        sE1[2048 + u] = W1[3 * 512 + u];
        sE1[2560 + u] = W1[4 * 512 + u];
    }
    __syncthreads();  // B1

    if (tid < 256) {
        const int t = tid >> 4, y = tid & 15;
        const int tgt = s_nbi[y];
        int p = -1;
        #pragma unroll
        for (int q = 0; q < 16; ++q) if (s_nbj[t][q] == tgt) p = q;
        s_P[t][y] = p;
        unsigned long long bal = __ballot(p >= 0);
        if (y == 0) {
            int vm = (int)((bal >> ((t & 3) * 16)) & 0xFFFFull);
            s_vm[t] = vm;
            s_m[t]  = (float)__popc(vm);
        }
    } else {
        const int u = tid;             // E1 entries 256..511
        float acc = 0.f;
        #pragma unroll
        for (int g = 6; g < 15; ++g) acc += W1[g * 512 + u];
        sE1[u]        = 16.f * W1[u] + W1[5 * 512 + u] + 16.f * acc;
        sE1[512 + u]  = W1[512 + u];
        sE1[1024 + u] = W1[15 * 512 + u];
        sE1[1536 + u] = 16.f * W1[2 * 512 + u];
        sE1[2048 + u] = W1[3 * 512 + u];
        sE1[2560 + u] = W1[4 * 512 + u];
    }
    __syncthreads();  // B2

    if (tid < 256) {
        // ---- half A: Z4/Z5 + 5 cooperative matvecs (lane y -> h=2y,2y+1) ----
        const int t = tid >> 4, y = tid & 15, x = t;
        float Y0[16];
        #pragma unroll
        for (int c4 = 0; c4 < 4; ++c4) {
            float4 v = *(const float4*)&sX[t][4 * c4];
            Y0[4*c4+0] = v.x; Y0[4*c4+1] = v.y; Y0[4*c4+2] = v.z; Y0[4*c4+3] = v.w;
        }
        float Z4[16], Z5[16];
        #pragma unroll
        for (int c = 0; c < 16; ++c) { Z4[c] = 0.f; Z5[c] = 0.f; }
        #pragma unroll
        for (int tp = 0; tp < 16; ++tp) {
            const int vm = s_vm[tp];
            const float mt = s_m[tp];
            const float fb = ((vm >> x) & 1) ? mt : 0.f;
            const float f5 = mt * mt;
            #pragma unroll
            for (int c4 = 0; c4 < 4; ++c4) {
                float4 v = *(const float4*)&sX[tp][4 * c4];
                Z4[4*c4+0] = fmaf(fb, v.x, Z4[4*c4+0]);
                Z4[4*c4+1] = fmaf(fb, v.y, Z4[4*c4+1]);
                Z4[4*c4+2] = fmaf(fb, v.z, Z4[4*c4+2]);
                Z4[4*c4+3] = fmaf(fb, v.w, Z4[4*c4+3]);
                Z5[4*c4+0] = fmaf(f5, v.x, Z5[4*c4+0]);
                Z5[4*c4+1] = fmaf(f5, v.y, Z5[4*c4+1]);
                Z5[4*c4+2] = fmaf(f5, v.z, Z5[4*c4+2]);
                Z5[4*c4+3] = fmaf(f5, v.w, Z5[4*c4+3]);
            }
        }
        const float m = s_m[t];
        float v0a=0.f,v0b=0.f,v1a=0.f,v1b=0.f,v2a=0.f,v2b=0.f;
        float v3a=0.f,v3b=0.f,v4a=0.f,v4b=0.f;
        const float2* Wsb = (const float2*)(sE1 + 0 * 512);
        const float2* Wab = (const float2*)(sE1 + 1 * 512);
        const float2* W16 = (const float2*)(sE1 + 2 * 512);
        const float2* Wtb = (const float2*)(sE1 + 4 * 512);
        const float2* Wal = (const float2*)(sE1 + 5 * 512);
        #pragma unroll
        for (int c = 0; c < 16; ++c) {
            const float cf0 = m * Y0[c];
            const float cf1 = m * cf0;
            const float cf2 = Y0[c];
            const float cf3 = Z4[c];
            const float cf4 = Z5[c];
            const int idx = c * 16 + y;
            float2 w0 = Wsb[idx]; v0a = fmaf(cf0, w0.x, v0a); v0b = fmaf(cf0, w0.y, v0b);
            float2 w1 = Wab[idx]; v1a = fmaf(cf1, w1.x, v1a); v1b = fmaf(cf1, w1.y, v1b);
            float2 w2 = W16[idx]; v2a = fmaf(cf2, w2.x, v2a); v2b = fmaf(cf2, w2.y, v2b);
            float2 w3 = Wtb[idx]; v3a = fmaf(cf3, w3.x, v3a); v3b = fmaf(cf3, w3.y, v3b);
            float2 w4 = Wal[idx]; v4a = fmaf(cf4, w4.x, v4a); v4b = fmaf(cf4, w4.y, v4b);
        }
        *(float2*)&sV[t][0 * 32 + 2 * y] = make_float2(v0a, v0b);
        *(float2*)&sV[t][1 * 32 + 2 * y] = make_float2(v1a, v1b);
        *(float2*)&sV[t][2 * 32 + 2 * y] = make_float2(v2a, v2b);
        *(float2*)&sV[t][3 * 32 + 2 * y] = make_float2(v3a, v3b);
        *(float2*)&sV[t][4 * 32 + 2 * y] = make_float2(v4a, v4b);
    } else {
        // ---- half B: Z2 + Wt2 readlane-matmul ----
        const int w = tid - 256;
        const int t = w >> 4, y = w & 15, x = t;
        float Z2[16];
        #pragma unroll
        for (int c = 0; c < 16; ++c) Z2[c] = 0.f;
        #pragma unroll
        for (int tp = 0; tp < 16; ++tp) {
            const int vm = s_vm[tp];
            const float f2 = (float)((vm >> x) & (vm >> y) & 1);
            #pragma unroll
            for (int c4 = 0; c4 < 4; ++c4) {
                float4 v = *(const float4*)&sX[tp][4 * c4];
                Z2[4*c4+0] = fmaf(f2, v.x, Z2[4*c4+0]);
                Z2[4*c4+1] = fmaf(f2, v.y, Z2[4*c4+1]);
                Z2[4*c4+2] = fmaf(f2, v.z, Z2[4*c4+2]);
                Z2[4*c4+3] = fmaf(f2, v.w, Z2[4*c4+3]);
            }
        }
        float pp[HH];
        #pragma unroll
        for (int h = 0; h < HH; ++h) pp[h] = 0.f;
        MM_RL(sE1 + 3 * 512, 2, Z2[ci], pp);
        float* dst = &sPP[(t * 16 + y) * 36];
        #pragma unroll
        for (int h4 = 0; h4 < 8; ++h4)
            *(float4*)&dst[4 * h4] = make_float4(pp[4*h4], pp[4*h4+1], pp[4*h4+2], pp[4*h4+3]);
    }
    __syncthreads();  // B3

    float fr[HH];   // final relu'd output (half A only)
    if (tid < 256) {
        const int t = tid >> 4, y = tid & 15, x = t;
        const float vy  = (s_P[t][y] >= 0) ? 1.f : 0.f;
        const float dxy = (x == y) ? 1.f : 0.f;
        const float* pp = &sPP[(t * 16 + y) * 36];
        #pragma unroll
        for (int h4 = 0; h4 < 8; ++h4) {
            const float4 V0 = *(const float4*)&sV[t][0 * 32 + 4 * h4];
            const float4 V1 = *(const float4*)&sV[t][1 * 32 + 4 * h4];
            const float4 V2 = *(const float4*)&sV[t][2 * 32 + 4 * h4];
            const float4 V3 = *(const float4*)&sV[t][3 * 32 + 4 * h4];
            const float4 V4 = *(const float4*)&sV[t][4 * 32 + 4 * h4];
            const float4 PP = *(const float4*)&pp[4 * h4];
            float a_ = vy*(V0.x+V2.x) + V1.x + V3.x + dxy*V4.x + PP.x + bias[4*h4+0];
            float b_ = vy*(V0.y+V2.y) + V1.y + V3.y + dxy*V4.y + PP.y + bias[4*h4+1];
            float c_ = vy*(V0.z+V2.z) + V1.z + V3.z + dxy*V4.z + PP.z + bias[4*h4+2];
            float d_ = vy*(V0.w+V2.w) + V1.w + V3.w + dxy*V4.w + PP.w + bias[4*h4+3];
            fr[4*h4+0] = a_ > 0.f ? a_ : 0.f;
            fr[4*h4+1] = b_ > 0.f ? b_ : 0.f;
            fr[4*h4+2] = c_ > 0.f ? c_ : 0.f;
            fr[4*h4+3] = d_ > 0.f ? d_ : 0.f;
        }
    }
    __syncthreads();  // B4 (all sPP half-B reads done)

    if (tid < 256) {
        // park at slot (q=y)*16+(p=x) so storer reads are slot-stride-1
        const int t = tid >> 4, y = tid & 15;
        float* dst = &sPP[(y * 16 + t) * 36];
        #pragma unroll
        for (int h4 = 0; h4 < 8; ++h4)
            *(float4*)&dst[4 * h4] = make_float4(fr[4*h4], fr[4*h4+1], fr[4*h4+2], fr[4*h4+3]);
    }
    __syncthreads();  // B5

    if (tid < 256) {
        // storer (q,p): p in low lane bits -> coalesced 256 B segments
        const int q = tid >> 4, p = tid & 15;
        const float* src = &sPP[(q * 16 + p) * 36];
        float4* F4 = (float4*)F1c;
        const size_t basec = ((size_t)i * 16 + q) * 128 + p;
        #pragma unroll
        for (int c4 = 0; c4 < 8; ++c4)
            F4[basec + c4 * 16] = *(const float4*)&src[4 * c4];
    }
}

// ---------------- layer 2 ----------------
// E2 slices (1024 floats each): 0:Wsb 1:Wab 2:W16 3:Wt2 4:Wtb 5:Wal
// F1c chunk (j*16+q)*128 + c4*16 + p = channels 4c4..4c4+3 of F1[j][p][q][:].
__global__ __launch_bounds__(512)
void ccn_l2(const float* __restrict__ F1c, const int* __restrict__ nbrs,
            const float* __restrict__ W2, const float* __restrict__ bias,
            const float* __restrict__ fcw, const float* __restrict__ fcb,
            float* __restrict__ out)
{
    __shared__ float sE2[6 * 1024];    // 24 KB
    __shared__ float sRpp[256 * 36];   // 36 KB: R rows, then half-B pp results
    __shared__ float s_stb[16 * 33];
    __shared__ float s_sall[C2];
    __shared__ int   s_nbi[16];
    __shared__ int   s_PQ[16 * 17];    // nbj, then overwritten with P (wave-local)
    __shared__ float s_red[4];

    const int tid  = threadIdx.x;
    const int i    = ((blockIdx.x & 7) << 5) | (blockIdx.x >> 3);  // XCD swizzle
    const int lane = tid & 63;
    const float4* F4 = (const float4*)F1c;

    if (tid < 16) s_nbi[tid] = nbrs[i * 16 + tid];
    __syncthreads();  // B0

    if (tid < 256) {
        const int t = tid >> 4, y = tid & 15;
        const int j = s_nbi[t];
        s_PQ[t * 17 + y] = nbrs[j * 16 + y];
    } else {
        const int w = tid - 256;
        #pragma unroll
        for (int k = 0; k < 2; ++k) {
            const int u = w + k * 256;          // E2 entries 0..511
            float acc = 0.f;
            #pragma unroll
            for (int g = 6; g < 15; ++g) acc += W2[g * 1024 + u];
            sE2[u]        = 16.f * W2[u] + W2[5 * 1024 + u] + 16.f * acc;
            sE2[1024 + u] = W2[1024 + u];
            sE2[2048 + u] = W2[15 * 1024 + u];
            sE2[3072 + u] = 16.f * W2[2 * 1024 + u];
            sE2[4096 + u] = W2[3 * 1024 + u];
            sE2[5120 + u] = W2[4 * 1024 + u];
        }
    }
    __syncthreads();  // B1

    if (tid < 256) {
        const int t = tid >> 4, y = tid & 15;
        const int tgt = s_nbi[y];
        int p = -1;
        #pragma unroll
        for (int q = 0; q < 16; ++q) if (s_PQ[t * 17 + q] == tgt) p = q;
        s_PQ[t * 17 + y] = p;   // overwrite: reads above precede write (wave lockstep)
    } else {
        const int w = tid - 256;
        #pragma unroll
        for (int k = 2; k < 4; ++k) {
            const int u = w + k * 256;          // E2 entries 512..1023
            float acc = 0.f;
            #pragma unroll
            for (int g = 6; g < 15; ++g) acc += W2[g * 1024 + u];
            sE2[u]        = 16.f * W2[u] + W2[5 * 1024 + u] + 16.f * acc;
            sE2[1024 + u] = W2[1024 + u];
            sE2[2048 + u] = W2[15 * 1024 + u];
            sE2[3072 + u] = 16.f * W2[2 * 1024 + u];
            sE2[4096 + u] = W2[3 * 1024 + u];
            sE2[5120 + u] = W2[4 * 1024 + u];
        }
    }
    __syncthreads();  // B2

    float pre[HH];
    float sab[C2];
    float pp[HH];

    if (tid < 256) {
        // ---- half A: R gather + Wsb/W16 readlane matmuls ----
        const int t = tid >> 4, y = tid & 15;
        const int j = s_nbi[t];
        const int p = s_PQ[t * 17 + y];
        const float mp = (p >= 0) ? 1.f : 0.f;
        const int pc = p >= 0 ? p : 0;
        const size_t jbase = (size_t)j * 2048;   // 16*128 chunks per tile

        float R[C2];
        #pragma unroll
        for (int c = 0; c < C2; ++c) R[c] = 0.f;
        #pragma unroll
        for (int b = 0; b < 16; ++b) {
            const int q = s_PQ[t * 17 + b];
            const float mm = (q >= 0) ? mp : 0.f;
            const int qc = q >= 0 ? q : 0;
            const size_t rb = jbase + (size_t)qc * 128 + pc;
            #pragma unroll
            for (int c4 = 0; c4 < 8; ++c4) {
                float4 v = F4[rb + c4 * 16];
                R[4*c4+0] = fmaf(mm, v.x, R[4*c4+0]);
                R[4*c4+1] = fmaf(mm, v.y, R[4*c4+1]);
                R[4*c4+2] = fmaf(mm, v.z, R[4*c4+2]);
                R[4*c4+3] = fmaf(mm, v.w, R[4*c4+3]);
            }
        }
        #pragma unroll
        for (int c4 = 0; c4 < 8; ++c4)
            *(float4*)&sRpp[(t * 16 + y) * 36 + 4 * c4] =
                make_float4(R[4*c4+0], R[4*c4+1], R[4*c4+2], R[4*c4+3]);

        #pragma unroll
        for (int h = 0; h < HH; ++h) pre[h] = 0.f;
        MM_RL(sE2 + 0 * 1024, 4, R[ci], pre);          // Wsb^T R

        #pragma unroll
        for (int c = 0; c < C2; ++c) {
            float s = R[c];
            s += __shfl_xor(s, 1);
            s += __shfl_xor(s, 2);
            s += __shfl_xor(s, 4);
            s += __shfl_xor(s, 8);
            sab[c] = s;
        }

        float D[C2];
        {
            const size_t db = jbase + (size_t)pc * 128 + pc;
            #pragma unroll
            for (int c4 = 0; c4 < 8; ++c4) {
                float4 v = F4[db + c4 * 16];
                D[4*c4+0] = mp * v.x; D[4*c4+1] = mp * v.y;
                D[4*c4+2] = mp * v.z; D[4*c4+3] = mp * v.w;
            }
        }
        MM_RL(sE2 + 2 * 1024, 4, D[ci], pre);          // W16^T D
    } else {
        // ---- half B: ST gather + Wt2 readlane matmul ----
        const int w = tid - 256;
        const int g = w >> 4, l = w & 15;              // output (x=l, y=g)
        float ST[C2];
        #pragma unroll
        for (int c = 0; c < C2; ++c) ST[c] = 0.f;
        #pragma unroll
        for (int tp = 0; tp < 16; ++tp) {
            const int jt = s_nbi[tp];
            const int py = s_PQ[tp * 17 + g];          // group-uniform
            const int px = s_PQ[tp * 17 + l];          // lane-varying
            const float mm = (px >= 0 && py >= 0) ? 1.f : 0.f;
            const int pyc = py >= 0 ? py : 0;
            const int pxc = px >= 0 ? px : 0;
            const size_t rb = (size_t)jt * 2048 + (size_t)pyc * 128 + pxc;
            #pragma unroll
            for (int c4 = 0; c4 < 8; ++c4) {
                float4 v = F4[rb + c4 * 16];
                ST[4*c4+0] = fmaf(mm, v.x, ST[4*c4+0]);
                ST[4*c4+1] = fmaf(mm, v.y, ST[4*c4+1]);
                ST[4*c4+2] = fmaf(mm, v.z, ST[4*c4+2]);
                ST[4*c4+3] = fmaf(mm, v.w, ST[4*c4+3]);
            }
        }
        #pragma unroll
        for (int h = 0; h < HH; ++h) pp[h] = 0.f;
        MM_RL(sE2 + 3 * 1024, 4, ST[ci], pp);          // Wt2^T ST
    }
    __syncthreads();  // B3  (sR rows complete)

    if (tid < 256) {
        // stb[x2][c] = sum_t R[t][x2][c]
        #pragma unroll
        for (int k = 0; k < 2; ++k) {
            const int x2 = (tid >> 5) + 8 * k;
            const int c = tid & 31;
            float s = 0.f;
            #pragma unroll
            for (int tt = 0; tt < 16; ++tt) s += sRpp[(tt * 16 + x2) * 36 + c];
            s_stb[x2 * 33 + c] = s;
        }
    }
    __syncthreads();  // B4  (stb complete; sR now dead)

    if (tid < 256) {
        if (tid < 32) {
            float s = 0.f;
            #pragma unroll
            for (int x2 = 0; x2 < 16; ++x2) s += s_stb[x2 * 33 + tid];
            s_sall[tid] = s;
        }
    } else {
        // half B parks its pp into the dead sR buffer at row x*16+y = l*16+g
        const int w = tid - 256;
        const int g = w >> 4, l = w & 15;
        float* dst = &sRpp[(l * 16 + g) * 36];
        #pragma unroll
        for (int h4 = 0; h4 < 8; ++h4)
            *(float4*)&dst[4 * h4] = make_float4(pp[4*h4], pp[4*h4+1], pp[4*h4+2], pp[4*h4+3]);
    }
    __syncthreads();  // B5

    if (tid < 256) {
        const int t = tid >> 4, y = tid & 15, x = t;
        const float dxy = (x == y) ? 1.f : 0.f;
        // cooperative matvecs Wab/Wtb/Wal (lane y -> h=2y,2y+1), combine via shfl
        float S0 = 0.f, S1 = 0.f, L0 = 0.f, L1 = 0.f;
        {
            const float2* Wab = (const float2*)(sE2 + 1 * 1024);
            const float2* Wtb = (const float2*)(sE2 + 4 * 1024);
            const float2* Wal = (const float2*)(sE2 + 5 * 1024);
            #pragma unroll
            for (int c = 0; c < C2; ++c) {
                const float cfa = sab[c];
                const float cft = s_stb[t * 33 + c];
                const float cfl = s_sall[c];
                const int idx = c * 16 + y;
                float2 wa = Wab[idx]; S0 = fmaf(cfa, wa.x, S0); S1 = fmaf(cfa, wa.y, S1);
                float2 wt = Wtb[idx]; S0 = fmaf(cft, wt.x, S0); S1 = fmaf(cft, wt.y, S1);
                float2 wl = Wal[idx]; L0 = fmaf(cfl, wl.x, L0); L1 = fmaf(cfl, wl.y, L1);
            }
        }
        const int gbase = (t & 3) * 16;
        #pragma unroll
        for (int h = 0; h < HH; ++h) {
            const int src = gbase + (h >> 1);
            const float sv = (h & 1) ? S1 : S0;
            const float lv = (h & 1) ? L1 : L0;
            pre[h] += __shfl(sv, src, 64) + dxy * __shfl(lv, src, 64);
        }
        // pick up half B's Wt2 contribution (row t*16+y)
        {
            const float* ppr = &sRpp[(t * 16 + y) * 36];
            #pragma unroll
            for (int h4 = 0; h4 < 8; ++h4) {
                const float4 v = *(const float4*)&ppr[4 * h4];
                pre[4*h4+0] += v.x; pre[4*h4+1] += v.y;
                pre[4*h4+2] += v.z; pre[4*h4+3] += v.w;
            }
        }
        // epilogue: bias, relu, dot fcw, wave reduce
        float local = 0.f;
        #pragma unroll
        for (int h = 0; h < HH; ++h) {
            float v = pre[h] + bias[h];
            v = v > 0.f ? v : 0.f;
            local += v * fcw[h];
        }
        #pragma unroll
        for (int off = 32; off > 0; off >>= 1) local += __shfl_down(local, off, 64);
        if (lane == 0) s_red[tid >> 6] = local;
    }
    __syncthreads();  // B6
    if (tid == 0) {
        const float v = s_red[0] + s_red[1] + s_red[2] + s_red[3]
                      + fcb[0] * (1.f / 256.f);
        atomicAdd(out, v);
    }
}

extern "C" void kernel_launch(void* const* d_in, const int* in_sizes, int n_in,
                              void* d_out, int out_size, void* d_ws, size_t ws_size,
                              hipStream_t stream) {
    const float* X    = (const float*)d_in[0];
    const int*   nbrs = (const int*)  d_in[1];
    const float* W1   = (const float*)d_in[2];
    const float* b1   = (const float*)d_in[3];
    const float* W2   = (const float*)d_in[4];
    const float* b2   = (const float*)d_in[5];
    const float* fc_w = (const float*)d_in[6];
    const float* fc_b = (const float*)d_in[7];
    float* outp = (float*)d_out;

    float* F1c = (float*)d_ws;   // 256*16*16*32 floats = 8 MB

    ccn_l1<<<NV, 512, 0, stream>>>(X, nbrs, W1, b1, F1c, outp);
    ccn_l2<<<NV, 512, 0, stream>>>(F1c, nbrs, W2, b2, fc_w, fc_b, outp);
}